// Round 4
// baseline (238.032 us; speedup 1.0000x reference)
//
#include <hip/hip_runtime.h>
#include <hip/hip_bf16.h>
#include <stdint.h>

// Problem constants
#define B_   2
#define H_   16
#define N_   2048
#define D_   1024
#define DH   64
#define MTOK 4096   // B_*N_

#define LOG2E 1.44269504088896f

typedef __attribute__((ext_vector_type(8)))  short bf16x8;
typedef __attribute__((ext_vector_type(4)))  float f32x4;
typedef __attribute__((ext_vector_type(16))) float f32x16;
typedef __attribute__((ext_vector_type(2)))  unsigned u32x2;
typedef __attribute__((ext_vector_type(4)))  unsigned short us4;

static __device__ __forceinline__ unsigned short f2bf(float f) {
    union { float f; unsigned u; } v; v.f = f;
    unsigned r = v.u + 0x7fffu + ((v.u >> 16) & 1u);
    return (unsigned short)(r >> 16);
}

static __device__ __forceinline__ unsigned cvt_pk_bf16(float lo, float hi) {
    unsigned r;
    asm("v_cvt_pk_bf16_f32 %0, %1, %2" : "=v"(r) : "v"(lo), "v"(hi));
    return r;
}

static __device__ __forceinline__ bf16x8 frag_from_u32(unsigned a, unsigned b, unsigned c, unsigned d) {
    union { unsigned u[4]; bf16x8 v; } x;
    x.u[0] = a; x.u[1] = b; x.u[2] = c; x.u[3] = d;
    return x.v;
}

static __device__ __forceinline__ void load_lds16(const void* g, void* l) {
    __builtin_amdgcn_global_load_lds(
        (const __attribute__((address_space(1))) unsigned int*)g,
        (__attribute__((address_space(3))) unsigned int*)l, 16, 0, 0);
}

// ---------------- fp32 -> bf16 elementwise (x) ----------------
__global__ __launch_bounds__(256) void k_cvt_x(const float* __restrict__ x,
                                               unsigned short* __restrict__ xb, int n) {
    int idx = (blockIdx.x * 256 + threadIdx.x) * 4;
    if (idx < n) {
        float4 v = *(const float4*)(x + idx);
        us4 o;
        o.x = f2bf(v.x); o.y = f2bf(v.y); o.z = f2bf(v.z); o.w = f2bf(v.w);
        *(us4*)(xb + idx) = o;
    }
}

// ------------- fp32 [R][C] -> bf16 [C][R] (weights) -------------
__global__ __launch_bounds__(256) void k_transpose_w(const float* __restrict__ in,
                                                     unsigned short* __restrict__ out,
                                                     int R, int C) {
    __shared__ float tile[64][65];
    int c0 = blockIdx.x * 64, r0 = blockIdx.y * 64;
    int t = threadIdx.x;
    int tr = t >> 4, tc = (t & 15) * 4;
#pragma unroll
    for (int p = 0; p < 4; p++) {
        int row = p * 16 + tr;
        float4 v = *(const float4*)(in + (size_t)(r0 + row) * C + c0 + tc);
        tile[row][tc + 0] = v.x; tile[row][tc + 1] = v.y;
        tile[row][tc + 2] = v.z; tile[row][tc + 3] = v.w;
    }
    __syncthreads();
    int oc = t >> 4, orr = (t & 15) * 4;
#pragma unroll
    for (int p = 0; p < 4; p++) {
        int crow = p * 16 + oc;   // original column == output row
        us4 o;
        o.x = f2bf(tile[orr + 0][crow]);
        o.y = f2bf(tile[orr + 1][crow]);
        o.z = f2bf(tile[orr + 2][crow]);
        o.w = f2bf(tile[orr + 3][crow]);
        *(us4*)(out + (size_t)(c0 + crow) * R + r0 + orr) = o;
    }
}

// ---------------- m97-style 128x128 GEMM, BK=64 ----------------
// MODE 0: A = xb [4096][1024], Bt = w1t [3072][1024]; epilogue: +b1,
//   q (scaled by 0.125*log2e) -> qh [B][H][N][DH] bf16,
//   k -> ks fragment-major, v -> vs fragment-major (see k_attn).
// MODE 1: A = attn [B*H][N][DH] (head-strided k), Bt = w2t [1024][1024];
//   epilogue: +b2 -> fp32 out [4096][1024].
template <int MODE>
__global__ __launch_bounds__(256) void k_gemm(const unsigned short* __restrict__ A,
                                              const unsigned short* __restrict__ Bt,
                                              const float* __restrict__ bias,
                                              unsigned short* __restrict__ qdst,
                                              unsigned short* __restrict__ kdst,
                                              unsigned short* __restrict__ vdst,
                                              float* __restrict__ outp) {
    __shared__ unsigned short As[128 * 64];
    __shared__ unsigned short Bs[128 * 64];
    const int K = 1024;
    int tid = threadIdx.x;
    int lane = tid & 63, wv = tid >> 6;
    int wm = wv >> 1, wn = wv & 1;
    int m0 = blockIdx.y * 128;
    int n0 = blockIdx.x * 128;
    int bIdx = m0 >> 11;       // batch index (MODE 1)
    int ntok0 = m0 & 2047;

    f32x4 acc[4][4];
#pragma unroll
    for (int i = 0; i < 4; i++)
#pragma unroll
        for (int j = 0; j < 4; j++) {
            f32x4 z; z[0] = 0.f; z[1] = 0.f; z[2] = 0.f; z[3] = 0.f;
            acc[i][j] = z;
        }

#pragma unroll 1
    for (int k0 = 0; k0 < K; k0 += 64) {
        const unsigned short* aptr;
        int arst;
        if (MODE == 0) { aptr = A + (size_t)m0 * K + k0; arst = K; }
        else {
            int hh = k0 >> 6;
            aptr = A + ((size_t)(bIdx * H_ + hh) * N_ + ntok0) * DH;
            arst = DH;
        }
        const unsigned short* bptr = Bt + (size_t)n0 * K + k0;
#pragma unroll
        for (int i = 0; i < 4; i++) {
            int cidb = i * 256 + wv * 64;          // wave-uniform chunk base
            int cid = cidb + lane;
            load_lds16(aptr + (size_t)(cid >> 3) * arst + (cid & 7) * 8, &As[cidb * 8]);
            load_lds16(bptr + (size_t)(cid >> 3) * K + (cid & 7) * 8, &Bs[cidb * 8]);
        }
        __syncthreads();
#pragma unroll
        for (int kk = 0; kk < 2; ++kk) {
            bf16x8 af[4], bfr[4];
            int ko = kk * 32 + (lane >> 4) * 8;
#pragma unroll
            for (int mi = 0; mi < 4; mi++)
                af[mi] = *(const bf16x8*)&As[(wm * 64 + mi * 16 + (lane & 15)) * 64 + ko];
#pragma unroll
            for (int ni = 0; ni < 4; ni++)
                bfr[ni] = *(const bf16x8*)&Bs[(wn * 64 + ni * 16 + (lane & 15)) * 64 + ko];
#pragma unroll
            for (int mi = 0; mi < 4; mi++)
#pragma unroll
                for (int ni = 0; ni < 4; ni++)
                    acc[mi][ni] = __builtin_amdgcn_mfma_f32_16x16x32_bf16(
                        af[mi], bfr[ni], acc[mi][ni], 0, 0, 0);
        }
        __syncthreads();
    }

    // epilogue  (C/D: col = lane&15, row = (lane>>4)*4 + r)
#pragma unroll
    for (int ni = 0; ni < 4; ni++) {
        int col = n0 + wn * 64 + ni * 16 + (lane & 15);
        float bv = bias[col];
        if (MODE == 0) {
            int which = col >> 10;
            int hd = (col >> 6) & 15;
            int dh = col & 63;
            float scl = (which == 0) ? (0.125f * LOG2E) : 1.0f;
#pragma unroll
            for (int mi = 0; mi < 4; mi++) {
                int rbase = m0 + wm * 64 + mi * 16 + (lane >> 4) * 4;
#pragma unroll
                for (int r = 0; r < 4; r++) {
                    int tok = rbase + r;
                    int bb = tok >> 11, nn = tok & 2047;
                    float vvv = (acc[mi][ni][r] + bv) * scl;
                    size_t chunk = ((size_t)(bb * H_ + hd) * 64 + (nn >> 5)) * 2048;
                    if (which == 0) {
                        qdst[((size_t)(bb * H_ + hd) * N_ + nn) * DH + dh] = f2bf(vvv);
                    } else if (which == 1) {
                        // K fragment-major: lane = ((dh>>3)&1)*32 + (nn&31),
                        // frag = dh>>4, elem = dh&7
                        int lane2 = ((dh >> 3) & 1) * 32 + (nn & 31);
                        kdst[chunk + lane2 * 32 + (dh >> 4) * 8 + (dh & 7)] = f2bf(vvv);
                    } else {
                        // V fragment-major: lane = ((nn>>3)&1)*32 + (dh&31),
                        // frag = (dh>>5)*2 + ((nn>>4)&1), elem = nn&7
                        int lane2 = ((nn >> 3) & 1) * 32 + (dh & 31);
                        int islot = (dh >> 5) * 2 + ((nn >> 4) & 1);
                        vdst[chunk + lane2 * 32 + islot * 8 + (nn & 7)] = f2bf(vvv);
                    }
                }
            }
        } else {
#pragma unroll
            for (int mi = 0; mi < 4; mi++) {
                int rbase = m0 + wm * 64 + mi * 16 + (lane >> 4) * 4;
#pragma unroll
                for (int r = 0; r < 4; r++)
                    outp[(size_t)(rbase + r) * D_ + col] = acc[mi][ni][r] + bv;
            }
        }
    }
}

// one 32-kv attention step: QK^T (swapped) -> online softmax -> PV
#define ATTN_STEP(KF, VF)                                                         \
  do {                                                                            \
    f32x16 s;                                                                     \
    _Pragma("unroll") for (int r = 0; r < 16; r++) s[r] = 0.f;                    \
    s = __builtin_amdgcn_mfma_f32_32x32x16_bf16(KF[0], qf[0], s, 0, 0, 0);        \
    s = __builtin_amdgcn_mfma_f32_32x32x16_bf16(KF[1], qf[1], s, 0, 0, 0);        \
    s = __builtin_amdgcn_mfma_f32_32x32x16_bf16(KF[2], qf[2], s, 0, 0, 0);        \
    s = __builtin_amdgcn_mfma_f32_32x32x16_bf16(KF[3], qf[3], s, 0, 0, 0);        \
    float mx[8];                                                                  \
    _Pragma("unroll") for (int i = 0; i < 8; i++) mx[i] = fmaxf(s[i], s[i + 8]);  \
    _Pragma("unroll") for (int i = 0; i < 4; i++) mx[i] = fmaxf(mx[i], mx[i + 4]);\
    mx[0] = fmaxf(mx[0], mx[2]); mx[1] = fmaxf(mx[1], mx[3]);                     \
    float mt = fmaxf(mx[0], mx[1]);                                               \
    mt = fmaxf(mt, __shfl_xor(mt, 32));                                           \
    if (!__all(mt <= m + 8.0f)) {                                                 \
        float mn = fmaxf(m, mt);                                                  \
        float fs = __builtin_amdgcn_exp2f(m - mn);                                \
        m = mn;                                                                   \
        l *= fs;                                                                  \
        _Pragma("unroll") for (int r = 0; r < 16; r++) { o0[r] *= fs; o1[r] *= fs; } \
    }                                                                             \
    float p[16];                                                                  \
    _Pragma("unroll") for (int r = 0; r < 16; r++) p[r] = __builtin_amdgcn_exp2f(s[r] - m); \
    float sm[8];                                                                  \
    _Pragma("unroll") for (int i = 0; i < 8; i++) sm[i] = p[i] + p[i + 8];        \
    _Pragma("unroll") for (int i = 0; i < 4; i++) sm[i] = sm[i] + sm[i + 4];      \
    float sum = (sm[0] + sm[2]) + (sm[1] + sm[3]);                                \
    sum += __shfl_xor(sum, 32);                                                   \
    l += sum;                                                                     \
    unsigned pk[8];                                                               \
    _Pragma("unroll") for (int i = 0; i < 8; i++) pk[i] = cvt_pk_bf16(p[2 * i], p[2 * i + 1]); \
    u32x2 s0 = __builtin_amdgcn_permlane32_swap(pk[0], pk[2], false, false);      \
    u32x2 s1 = __builtin_amdgcn_permlane32_swap(pk[1], pk[3], false, false);      \
    u32x2 s2 = __builtin_amdgcn_permlane32_swap(pk[4], pk[6], false, false);      \
    u32x2 s3 = __builtin_amdgcn_permlane32_swap(pk[5], pk[7], false, false);      \
    bf16x8 pf0 = frag_from_u32(s0[0], s1[0], s0[1], s1[1]);                       \
    bf16x8 pf1 = frag_from_u32(s2[0], s3[0], s2[1], s3[1]);                       \
    o0 = __builtin_amdgcn_mfma_f32_32x32x16_bf16(VF[0], pf0, o0, 0, 0, 0);        \
    o0 = __builtin_amdgcn_mfma_f32_32x32x16_bf16(VF[1], pf1, o0, 0, 0, 0);        \
    o1 = __builtin_amdgcn_mfma_f32_32x32x16_bf16(VF[2], pf0, o1, 0, 0, 0);        \
    o1 = __builtin_amdgcn_mfma_f32_32x32x16_bf16(VF[3], pf1, o1, 0, 0, 0);        \
  } while (0)

// ---------------- flash attention, fragment-major K/V, 2-way KV split ----------------
// qh: [B][H][N][DH] bf16 (scaled 0.125*log2e); ks, vs: fragment-major
//   chunk(bh, t) = 2048 el; within chunk: lane*32 + frag*8 + elem.
// o: [B*H][N][DH] bf16
__global__ __launch_bounds__(256, 4) void k_attn(const unsigned short* __restrict__ qh,
                                                 const unsigned short* __restrict__ ks,
                                                 const unsigned short* __restrict__ vs,
                                                 unsigned short* __restrict__ o) {
    __shared__ float red[2][64][34];   // [qsub][lane][o0 16 | o1 16 | m | l]
    int tid = threadIdx.x;
    int lane = tid & 63, wv = tid >> 6;
    int qsub = wv >> 1;     // which 32-row q subtile
    int kvh  = wv & 1;      // which kv half
    int bh = blockIdx.y;
    int q0 = blockIdx.x * 64 + qsub * 32;
    const size_t bhO = (size_t)bh * N_ * DH;
    int ln = lane & 31, hi = lane >> 5;

    const unsigned short* qp = qh + bhO;
    bf16x8 qf[4];
#pragma unroll
    for (int kk = 0; kk < 4; kk++)
        qf[kk] = *(const bf16x8*)(qp + (size_t)(q0 + ln) * DH + kk * 16 + hi * 8);

    // dense per-wave pointers: each step's fragments are a contiguous 1KB x 4
    const unsigned short* kptr = ks + (size_t)bh * 131072 + (size_t)(kvh * 32) * 2048 + lane * 32;
    const unsigned short* vptr = vs + (size_t)bh * 131072 + (size_t)(kvh * 32) * 2048 + lane * 32;

    f32x16 o0, o1;
#pragma unroll
    for (int r = 0; r < 16; r++) { o0[r] = 0.f; o1[r] = 0.f; }
    float m = -INFINITY, l = 0.f;

    bf16x8 ka[4], va[4], kb[4], vb[4];
#pragma unroll
    for (int i = 0; i < 4; i++) {
        ka[i] = *(const bf16x8*)(kptr + i * 8);
        va[i] = *(const bf16x8*)(vptr + i * 8);
    }

#pragma unroll 1
    for (int s5 = 0; s5 < 32; s5 += 2) {
#pragma unroll
        for (int i = 0; i < 4; i++) {
            kb[i] = *(const bf16x8*)(kptr + 2048 + i * 8);
            vb[i] = *(const bf16x8*)(vptr + 2048 + i * 8);
        }
        ATTN_STEP(ka, va);
        kptr += 4096; vptr += 4096;
#pragma unroll
        for (int i = 0; i < 4; i++) {
            ka[i] = *(const bf16x8*)(kptr + i * 8);
            va[i] = *(const bf16x8*)(vptr + i * 8);
        }
        ATTN_STEP(kb, vb);
    }

    // merge kv-halves: kvh==1 publishes, kvh==0 combines + writes
    if (kvh == 1) {
#pragma unroll
        for (int r = 0; r < 16; r++) {
            red[qsub][lane][r] = o0[r];
            red[qsub][lane][16 + r] = o1[r];
        }
        red[qsub][lane][32] = m;
        red[qsub][lane][33] = l;
    }
    __syncthreads();
    if (kvh == 0) {
        float mb = red[qsub][lane][32], lb = red[qsub][lane][33];
        float mn = fmaxf(m, mb);
        float fa = __builtin_amdgcn_exp2f(m - mn);
        float fb = __builtin_amdgcn_exp2f(mb - mn);
        float inv = 1.0f / (l * fa + lb * fb);
        float ga = fa * inv, gb = fb * inv;
        unsigned short* ob = o + bhO + (size_t)(q0 + ln) * DH;
#pragma unroll
        for (int t = 0; t < 2; t++) {
#pragma unroll
            for (int g = 0; g < 4; g++) {
                int d = t * 32 + g * 8 + hi * 4;   // rows: (r&3)+8*(r>>2)+4*hi
                int rb = g * 4;
                float a0 = (t ? o1[rb + 0] : o0[rb + 0]) * ga + red[qsub][lane][t * 16 + rb + 0] * gb;
                float a1 = (t ? o1[rb + 1] : o0[rb + 1]) * ga + red[qsub][lane][t * 16 + rb + 1] * gb;
                float a2 = (t ? o1[rb + 2] : o0[rb + 2]) * ga + red[qsub][lane][t * 16 + rb + 2] * gb;
                float a3 = (t ? o1[rb + 3] : o0[rb + 3]) * ga + red[qsub][lane][t * 16 + rb + 3] * gb;
                us4 w;
                w.x = f2bf(a0); w.y = f2bf(a1); w.z = f2bf(a2); w.w = f2bf(a3);
                *(us4*)(ob + d) = w;
            }
        }
    }
}

extern "C" void kernel_launch(void* const* d_in, const int* in_sizes, int n_in,
                              void* d_out, int out_size, void* d_ws, size_t ws_size,
                              hipStream_t stream) {
    const float* x  = (const float*)d_in[0];
    const float* W1 = (const float*)d_in[1];
    const float* b1 = (const float*)d_in[2];
    const float* W2 = (const float*)d_in[3];
    const float* b2 = (const float*)d_in[4];
    float* out = (float*)d_out;

    char* ws = (char*)d_ws;
    unsigned short* xb   = (unsigned short*)(ws);                  //  8,388,608 B
    unsigned short* w1t  = (unsigned short*)(ws + 8388608);        //  6,291,456 B
    unsigned short* w2t  = (unsigned short*)(ws + 14680064);       //  2,097,152 B
    unsigned short* qh   = (unsigned short*)(ws + 16777216);       //  8,388,608 B
    unsigned short* ks   = (unsigned short*)(ws + 25165824);       //  8,388,608 B
    unsigned short* vsb  = (unsigned short*)(ws + 33554432);       //  8,388,608 B
    unsigned short* attn = (unsigned short*)(ws + 41943040);       //  8,388,608 B
    // total 50,331,648 B of d_ws used (ks/vs overrun by prefetch stays in-bounds)

    k_cvt_x<<<4096, 256, 0, stream>>>(x, xb, MTOK * D_);
    k_transpose_w<<<dim3(48, 16), 256, 0, stream>>>(W1, w1t, D_, 3 * D_);
    k_transpose_w<<<dim3(16, 16), 256, 0, stream>>>(W2, w2t, D_, D_);
    k_gemm<0><<<dim3(24, 32), 256, 0, stream>>>(xb, w1t, b1, qh, ks, vsb, nullptr);
    k_attn<<<dim3(32, 32), 256, 0, stream>>>(qh, ks, vsb, attn);
    k_gemm<1><<<dim3(8, 32), 256, 0, stream>>>(attn, w2t, b2, nullptr, nullptr, nullptr, out);
}

// Round 5
// 206.300 us; speedup vs baseline: 1.1538x; 1.1538x over previous
//
#include <hip/hip_runtime.h>
#include <hip/hip_bf16.h>
#include <stdint.h>

// Problem constants
#define B_   2
#define H_   16
#define N_   2048
#define D_   1024
#define DH   64
#define MTOK 4096   // B_*N_

#define LOG2E 1.44269504088896f

typedef __attribute__((ext_vector_type(8)))  short bf16x8;
typedef __attribute__((ext_vector_type(4)))  float f32x4;
typedef __attribute__((ext_vector_type(16))) float f32x16;
typedef __attribute__((ext_vector_type(2)))  unsigned u32x2;
typedef __attribute__((ext_vector_type(4)))  unsigned short us4;

static __device__ __forceinline__ unsigned short f2bf(float f) {
    union { float f; unsigned u; } v; v.f = f;
    unsigned r = v.u + 0x7fffu + ((v.u >> 16) & 1u);
    return (unsigned short)(r >> 16);
}

static __device__ __forceinline__ unsigned cvt_pk_bf16(float lo, float hi) {
    unsigned r;
    asm("v_cvt_pk_bf16_f32 %0, %1, %2" : "=v"(r) : "v"(lo), "v"(hi));
    return r;
}

static __device__ __forceinline__ bf16x8 frag_from_u32(unsigned a, unsigned b, unsigned c, unsigned d) {
    union { unsigned u[4]; bf16x8 v; } x;
    x.u[0] = a; x.u[1] = b; x.u[2] = c; x.u[3] = d;
    return x.v;
}

static __device__ __forceinline__ void load_lds16(const void* g, void* l) {
    __builtin_amdgcn_global_load_lds(
        (const __attribute__((address_space(1))) unsigned int*)g,
        (__attribute__((address_space(3))) unsigned int*)l, 16, 0, 0);
}

// ---------------- fp32 -> bf16 elementwise (x) ----------------
__global__ __launch_bounds__(256) void k_cvt_x(const float* __restrict__ x,
                                               unsigned short* __restrict__ xb, int n) {
    int idx = (blockIdx.x * 256 + threadIdx.x) * 4;
    if (idx < n) {
        float4 v = *(const float4*)(x + idx);
        us4 o;
        o.x = f2bf(v.x); o.y = f2bf(v.y); o.z = f2bf(v.z); o.w = f2bf(v.w);
        *(us4*)(xb + idx) = o;
    }
}

// ------------- fp32 [R][C] -> bf16 [C][R] (weights) -------------
__global__ __launch_bounds__(256) void k_transpose_w(const float* __restrict__ in,
                                                     unsigned short* __restrict__ out,
                                                     int R, int C) {
    __shared__ float tile[64][65];
    int c0 = blockIdx.x * 64, r0 = blockIdx.y * 64;
    int t = threadIdx.x;
    int tr = t >> 4, tc = (t & 15) * 4;
#pragma unroll
    for (int p = 0; p < 4; p++) {
        int row = p * 16 + tr;
        float4 v = *(const float4*)(in + (size_t)(r0 + row) * C + c0 + tc);
        tile[row][tc + 0] = v.x; tile[row][tc + 1] = v.y;
        tile[row][tc + 2] = v.z; tile[row][tc + 3] = v.w;
    }
    __syncthreads();
    int oc = t >> 4, orr = (t & 15) * 4;
#pragma unroll
    for (int p = 0; p < 4; p++) {
        int crow = p * 16 + oc;   // original column == output row
        us4 o;
        o.x = f2bf(tile[orr + 0][crow]);
        o.y = f2bf(tile[orr + 1][crow]);
        o.z = f2bf(tile[orr + 2][crow]);
        o.w = f2bf(tile[orr + 3][crow]);
        *(us4*)(out + (size_t)(c0 + crow) * R + r0 + orr) = o;
    }
}

// ---------------- m97-style 128x128 GEMM, BK=64 ----------------
// MODE 0: A = xb [4096][1024], Bt = w1t [3072][1024]; epilogue: +b1,
//   q (scaled by 0.125*log2e) -> qh [B][H][N][DH] bf16,
//   k -> ks fragment-interleaved, v -> vs fragment-interleaved (see k_attn).
// MODE 1: A = attn [B*H][N][DH] (head-strided k), Bt = w2t [1024][1024];
//   epilogue: +b2 -> fp32 out [4096][1024].
template <int MODE>
__global__ __launch_bounds__(256) void k_gemm(const unsigned short* __restrict__ A,
                                              const unsigned short* __restrict__ Bt,
                                              const float* __restrict__ bias,
                                              unsigned short* __restrict__ qdst,
                                              unsigned short* __restrict__ kdst,
                                              unsigned short* __restrict__ vdst,
                                              float* __restrict__ outp) {
    __shared__ unsigned short As[128 * 64];
    __shared__ unsigned short Bs[128 * 64];
    const int K = 1024;
    int tid = threadIdx.x;
    int lane = tid & 63, wv = tid >> 6;
    int wm = wv >> 1, wn = wv & 1;
    int m0 = blockIdx.y * 128;
    int n0 = blockIdx.x * 128;
    int bIdx = m0 >> 11;       // batch index (MODE 1)
    int ntok0 = m0 & 2047;

    f32x4 acc[4][4];
#pragma unroll
    for (int i = 0; i < 4; i++)
#pragma unroll
        for (int j = 0; j < 4; j++) {
            f32x4 z; z[0] = 0.f; z[1] = 0.f; z[2] = 0.f; z[3] = 0.f;
            acc[i][j] = z;
        }

#pragma unroll 1
    for (int k0 = 0; k0 < K; k0 += 64) {
        const unsigned short* aptr;
        int arst;
        if (MODE == 0) { aptr = A + (size_t)m0 * K + k0; arst = K; }
        else {
            int hh = k0 >> 6;
            aptr = A + ((size_t)(bIdx * H_ + hh) * N_ + ntok0) * DH;
            arst = DH;
        }
        const unsigned short* bptr = Bt + (size_t)n0 * K + k0;
#pragma unroll
        for (int i = 0; i < 4; i++) {
            int cidb = i * 256 + wv * 64;          // wave-uniform chunk base
            int cid = cidb + lane;
            load_lds16(aptr + (size_t)(cid >> 3) * arst + (cid & 7) * 8, &As[cidb * 8]);
            load_lds16(bptr + (size_t)(cid >> 3) * K + (cid & 7) * 8, &Bs[cidb * 8]);
        }
        __syncthreads();
#pragma unroll
        for (int kk = 0; kk < 2; ++kk) {
            bf16x8 af[4], bfr[4];
            int ko = kk * 32 + (lane >> 4) * 8;
#pragma unroll
            for (int mi = 0; mi < 4; mi++)
                af[mi] = *(const bf16x8*)&As[(wm * 64 + mi * 16 + (lane & 15)) * 64 + ko];
#pragma unroll
            for (int ni = 0; ni < 4; ni++)
                bfr[ni] = *(const bf16x8*)&Bs[(wn * 64 + ni * 16 + (lane & 15)) * 64 + ko];
#pragma unroll
            for (int mi = 0; mi < 4; mi++)
#pragma unroll
                for (int ni = 0; ni < 4; ni++)
                    acc[mi][ni] = __builtin_amdgcn_mfma_f32_16x16x32_bf16(
                        af[mi], bfr[ni], acc[mi][ni], 0, 0, 0);
        }
        __syncthreads();
    }

    // epilogue  (C/D: col = lane&15, row = (lane>>4)*4 + r)
#pragma unroll
    for (int ni = 0; ni < 4; ni++) {
        int col = n0 + wn * 64 + ni * 16 + (lane & 15);
        float bv = bias[col];
        if (MODE == 0) {
            int which = col >> 10;
            int hd = (col >> 6) & 15;
            int dh = col & 63;
            float scl = (which == 0) ? (0.125f * LOG2E) : 1.0f;
#pragma unroll
            for (int mi = 0; mi < 4; mi++) {
                int rbase = m0 + wm * 64 + mi * 16 + (lane >> 4) * 4;
#pragma unroll
                for (int r = 0; r < 4; r++) {
                    int tok = rbase + r;
                    int bb = tok >> 11, nn = tok & 2047;
                    float vvv = (acc[mi][ni][r] + bv) * scl;
                    size_t chunk = ((size_t)(bb * H_ + hd) * 64 + (nn >> 5)) * 2048;
                    if (which == 0) {
                        qdst[((size_t)(bb * H_ + hd) * N_ + nn) * DH + dh] = f2bf(vvv);
                    } else if (which == 1) {
                        // K fragment-INTERLEAVED: [frag][lane][8el]
                        // lane = ((dh>>3)&1)*32 + (nn&31), frag = dh>>4, elem = dh&7
                        int lane2 = ((dh >> 3) & 1) * 32 + (nn & 31);
                        kdst[chunk + (dh >> 4) * 512 + lane2 * 8 + (dh & 7)] = f2bf(vvv);
                    } else {
                        // V fragment-INTERLEAVED: [islot][lane][8el]
                        // lane = ((nn>>3)&1)*32 + (dh&31),
                        // islot = (dh>>5)*2 + ((nn>>4)&1), elem = nn&7
                        int lane2 = ((nn >> 3) & 1) * 32 + (dh & 31);
                        int islot = (dh >> 5) * 2 + ((nn >> 4) & 1);
                        vdst[chunk + islot * 512 + lane2 * 8 + (nn & 7)] = f2bf(vvv);
                    }
                }
            }
        } else {
#pragma unroll
            for (int mi = 0; mi < 4; mi++) {
                int rbase = m0 + wm * 64 + mi * 16 + (lane >> 4) * 4;
#pragma unroll
                for (int r = 0; r < 4; r++)
                    outp[(size_t)(rbase + r) * D_ + col] = acc[mi][ni][r] + bv;
            }
        }
    }
}

// one 32-kv attention step: QK^T (swapped) -> online softmax -> PV
#define ATTN_STEP(KF, VF)                                                         \
  do {                                                                            \
    f32x16 s;                                                                     \
    _Pragma("unroll") for (int r = 0; r < 16; r++) s[r] = 0.f;                    \
    s = __builtin_amdgcn_mfma_f32_32x32x16_bf16(KF[0], qf[0], s, 0, 0, 0);        \
    s = __builtin_amdgcn_mfma_f32_32x32x16_bf16(KF[1], qf[1], s, 0, 0, 0);        \
    s = __builtin_amdgcn_mfma_f32_32x32x16_bf16(KF[2], qf[2], s, 0, 0, 0);        \
    s = __builtin_amdgcn_mfma_f32_32x32x16_bf16(KF[3], qf[3], s, 0, 0, 0);        \
    float mx[8];                                                                  \
    _Pragma("unroll") for (int i = 0; i < 8; i++) mx[i] = fmaxf(s[i], s[i + 8]);  \
    _Pragma("unroll") for (int i = 0; i < 4; i++) mx[i] = fmaxf(mx[i], mx[i + 4]);\
    mx[0] = fmaxf(mx[0], mx[2]); mx[1] = fmaxf(mx[1], mx[3]);                     \
    float mt = fmaxf(mx[0], mx[1]);                                               \
    mt = fmaxf(mt, __shfl_xor(mt, 32));                                           \
    if (!__all(mt <= m + 8.0f)) {                                                 \
        float mn = fmaxf(m, mt);                                                  \
        float fs = __builtin_amdgcn_exp2f(m - mn);                                \
        m = mn;                                                                   \
        l *= fs;                                                                  \
        _Pragma("unroll") for (int r = 0; r < 16; r++) { o0[r] *= fs; o1[r] *= fs; } \
    }                                                                             \
    float p[16];                                                                  \
    _Pragma("unroll") for (int r = 0; r < 16; r++) p[r] = __builtin_amdgcn_exp2f(s[r] - m); \
    float sm[8];                                                                  \
    _Pragma("unroll") for (int i = 0; i < 8; i++) sm[i] = p[i] + p[i + 8];        \
    _Pragma("unroll") for (int i = 0; i < 4; i++) sm[i] = sm[i] + sm[i + 4];      \
    float sum = (sm[0] + sm[2]) + (sm[1] + sm[3]);                                \
    sum += __shfl_xor(sum, 32);                                                   \
    l += sum;                                                                     \
    unsigned pk[8];                                                               \
    _Pragma("unroll") for (int i = 0; i < 8; i++) pk[i] = cvt_pk_bf16(p[2 * i], p[2 * i + 1]); \
    u32x2 s0 = __builtin_amdgcn_permlane32_swap(pk[0], pk[2], false, false);      \
    u32x2 s1 = __builtin_amdgcn_permlane32_swap(pk[1], pk[3], false, false);      \
    u32x2 s2 = __builtin_amdgcn_permlane32_swap(pk[4], pk[6], false, false);      \
    u32x2 s3 = __builtin_amdgcn_permlane32_swap(pk[5], pk[7], false, false);      \
    bf16x8 pf0 = frag_from_u32(s0[0], s1[0], s0[1], s1[1]);                       \
    bf16x8 pf1 = frag_from_u32(s2[0], s3[0], s2[1], s3[1]);                       \
    o0 = __builtin_amdgcn_mfma_f32_32x32x16_bf16(VF[0], pf0, o0, 0, 0, 0);        \
    o0 = __builtin_amdgcn_mfma_f32_32x32x16_bf16(VF[1], pf1, o0, 0, 0, 0);        \
    o1 = __builtin_amdgcn_mfma_f32_32x32x16_bf16(VF[2], pf0, o1, 0, 0, 0);        \
    o1 = __builtin_amdgcn_mfma_f32_32x32x16_bf16(VF[3], pf1, o1, 0, 0, 0);        \
  } while (0)

// ---------------- flash attention, fragment-interleaved K/V, 2-way KV split ----------------
// qh: [B][H][N][DH] bf16 (scaled 0.125*log2e); ks, vs: fragment-interleaved
//   chunk(bh, t) = 2048 el; within chunk: frag*512 + lane*8 + elem  (lane stride 16B!)
// o: [B*H][N][DH] bf16
// Grid: flat 1024 blocks, XCD-swizzled so each XCD owns 4 consecutive bh
// (K/V working set 2MB < 4MB per-XCD L2).
__global__ __launch_bounds__(256, 4) void k_attn(const unsigned short* __restrict__ qh,
                                                 const unsigned short* __restrict__ ks,
                                                 const unsigned short* __restrict__ vs,
                                                 unsigned short* __restrict__ o) {
    __shared__ float red[2][64][34];   // [qsub][lane][o0 16 | o1 16 | m | l]
    int tid = threadIdx.x;
    int lane = tid & 63, wv = tid >> 6;
    int qsub = wv >> 1;     // which 32-row q subtile
    int kvh  = wv & 1;      // which kv half
    // XCD swizzle: hw block F lands on XCD F%8; give XCD x logical work
    // L in [x*128, (x+1)*128) => bh in [4x, 4x+4)
    int F = blockIdx.x;
    int L = (F & 7) * 128 + (F >> 3);
    int bh = L >> 5;
    int q0 = (L & 31) * 64 + qsub * 32;
    const size_t bhO = (size_t)bh * N_ * DH;
    int ln = lane & 31, hi = lane >> 5;

    const unsigned short* qp = qh + bhO;
    bf16x8 qf[4];
#pragma unroll
    for (int kk = 0; kk < 4; kk++)
        qf[kk] = *(const bf16x8*)(qp + (size_t)(q0 + ln) * DH + kk * 16 + hi * 8);

    // dense per-wave pointers: every fragment load is a contiguous 1KB wave read
    const unsigned short* kptr = ks + (size_t)bh * 131072 + (size_t)(kvh * 32) * 2048 + lane * 8;
    const unsigned short* vptr = vs + (size_t)bh * 131072 + (size_t)(kvh * 32) * 2048 + lane * 8;

    f32x16 o0, o1;
#pragma unroll
    for (int r = 0; r < 16; r++) { o0[r] = 0.f; o1[r] = 0.f; }
    float m = -INFINITY, l = 0.f;

    bf16x8 ka[4], va[4], kb[4], vb[4];
#pragma unroll
    for (int i = 0; i < 4; i++) {
        ka[i] = *(const bf16x8*)(kptr + i * 512);
        va[i] = *(const bf16x8*)(vptr + i * 512);
    }

#pragma unroll 1
    for (int s5 = 0; s5 < 32; s5 += 2) {
#pragma unroll
        for (int i = 0; i < 4; i++) {
            kb[i] = *(const bf16x8*)(kptr + 2048 + i * 512);
            vb[i] = *(const bf16x8*)(vptr + 2048 + i * 512);
        }
        ATTN_STEP(ka, va);
        kptr += 4096; vptr += 4096;
#pragma unroll
        for (int i = 0; i < 4; i++) {
            ka[i] = *(const bf16x8*)(kptr + i * 512);
            va[i] = *(const bf16x8*)(vptr + i * 512);
        }
        ATTN_STEP(kb, vb);
    }

    // merge kv-halves: kvh==1 publishes, kvh==0 combines + writes
    if (kvh == 1) {
#pragma unroll
        for (int r = 0; r < 16; r++) {
            red[qsub][lane][r] = o0[r];
            red[qsub][lane][16 + r] = o1[r];
        }
        red[qsub][lane][32] = m;
        red[qsub][lane][33] = l;
    }
    __syncthreads();
    if (kvh == 0) {
        float mb = red[qsub][lane][32], lb = red[qsub][lane][33];
        float mn = fmaxf(m, mb);
        float fa = __builtin_amdgcn_exp2f(m - mn);
        float fb = __builtin_amdgcn_exp2f(mb - mn);
        float inv = 1.0f / (l * fa + lb * fb);
        float ga = fa * inv, gb = fb * inv;
        unsigned short* ob = o + bhO + (size_t)(q0 + ln) * DH;
#pragma unroll
        for (int t = 0; t < 2; t++) {
#pragma unroll
            for (int g = 0; g < 4; g++) {
                int d = t * 32 + g * 8 + hi * 4;   // rows: (r&3)+8*(r>>2)+4*hi
                int rb = g * 4;
                float a0 = (t ? o1[rb + 0] : o0[rb + 0]) * ga + red[qsub][lane][t * 16 + rb + 0] * gb;
                float a1 = (t ? o1[rb + 1] : o0[rb + 1]) * ga + red[qsub][lane][t * 16 + rb + 1] * gb;
                float a2 = (t ? o1[rb + 2] : o0[rb + 2]) * ga + red[qsub][lane][t * 16 + rb + 2] * gb;
                float a3 = (t ? o1[rb + 3] : o0[rb + 3]) * ga + red[qsub][lane][t * 16 + rb + 3] * gb;
                us4 w;
                w.x = f2bf(a0); w.y = f2bf(a1); w.z = f2bf(a2); w.w = f2bf(a3);
                *(us4*)(ob + d) = w;
            }
        }
    }
}

extern "C" void kernel_launch(void* const* d_in, const int* in_sizes, int n_in,
                              void* d_out, int out_size, void* d_ws, size_t ws_size,
                              hipStream_t stream) {
    const float* x  = (const float*)d_in[0];
    const float* W1 = (const float*)d_in[1];
    const float* b1 = (const float*)d_in[2];
    const float* W2 = (const float*)d_in[3];
    const float* b2 = (const float*)d_in[4];
    float* out = (float*)d_out;

    char* ws = (char*)d_ws;
    unsigned short* xb   = (unsigned short*)(ws);                  //  8,388,608 B
    unsigned short* w1t  = (unsigned short*)(ws + 8388608);        //  6,291,456 B
    unsigned short* w2t  = (unsigned short*)(ws + 14680064);       //  2,097,152 B
    unsigned short* qh   = (unsigned short*)(ws + 16777216);       //  8,388,608 B
    unsigned short* ks   = (unsigned short*)(ws + 25165824);       //  8,388,608 B
    unsigned short* vsb  = (unsigned short*)(ws + 33554432);       //  8,388,608 B
    unsigned short* attn = (unsigned short*)(ws + 41943040);       //  8,388,608 B

    k_cvt_x<<<4096, 256, 0, stream>>>(x, xb, MTOK * D_);
    k_transpose_w<<<dim3(48, 16), 256, 0, stream>>>(W1, w1t, D_, 3 * D_);
    k_transpose_w<<<dim3(16, 16), 256, 0, stream>>>(W2, w2t, D_, D_);
    k_gemm<0><<<dim3(24, 32), 256, 0, stream>>>(xb, w1t, b1, qh, ks, vsb, nullptr);
    k_attn<<<1024, 256, 0, stream>>>(qh, ks, vsb, attn);
    k_gemm<1><<<dim3(8, 32), 256, 0, stream>>>(attn, w2t, b2, nullptr, nullptr, nullptr, out);
}

// Round 6
// 149.029 us; speedup vs baseline: 1.5972x; 1.3843x over previous
//
#include <hip/hip_runtime.h>
#include <hip/hip_bf16.h>
#include <stdint.h>

// Problem constants
#define B_   2
#define H_   16
#define N_   2048
#define D_   1024
#define DH   64
#define MTOK 4096   // B_*N_

#define LOG2E 1.44269504088896f

typedef __attribute__((ext_vector_type(8)))  short bf16x8;
typedef __attribute__((ext_vector_type(4)))  float f32x4;
typedef __attribute__((ext_vector_type(16))) float f32x16;
typedef __attribute__((ext_vector_type(2)))  unsigned u32x2;
typedef __attribute__((ext_vector_type(4)))  unsigned short us4;

static __device__ __forceinline__ unsigned short f2bf(float f) {
    union { float f; unsigned u; } v; v.f = f;
    unsigned r = v.u + 0x7fffu + ((v.u >> 16) & 1u);
    return (unsigned short)(r >> 16);
}

static __device__ __forceinline__ unsigned f2u(float x) {
    union { float f; unsigned u; } v; v.f = x; return v.u;
}
static __device__ __forceinline__ float u2f(unsigned x) {
    union { unsigned u; float f; } v; v.u = x; return v.f;
}

static __device__ __forceinline__ unsigned cvt_pk_bf16(float lo, float hi) {
    unsigned r;
    asm("v_cvt_pk_bf16_f32 %0, %1, %2" : "=v"(r) : "v"(lo), "v"(hi));
    return r;
}

static __device__ __forceinline__ bf16x8 frag_from_u32(unsigned a, unsigned b, unsigned c, unsigned d) {
    union { unsigned u[4]; bf16x8 v; } x;
    x.u[0] = a; x.u[1] = b; x.u[2] = c; x.u[3] = d;
    return x.v;
}

static __device__ __forceinline__ void load_lds16(const void* g, void* l) {
    __builtin_amdgcn_global_load_lds(
        (const __attribute__((address_space(1))) unsigned int*)g,
        (__attribute__((address_space(3))) unsigned int*)l, 16, 0, 0);
}

// ---------------- fp32 -> bf16 elementwise (x) ----------------
__global__ __launch_bounds__(256) void k_cvt_x(const float* __restrict__ x,
                                               unsigned short* __restrict__ xb, int n) {
    int idx = (blockIdx.x * 256 + threadIdx.x) * 4;
    if (idx < n) {
        float4 v = *(const float4*)(x + idx);
        us4 o;
        o.x = f2bf(v.x); o.y = f2bf(v.y); o.z = f2bf(v.z); o.w = f2bf(v.w);
        *(us4*)(xb + idx) = o;
    }
}

// ------------- fp32 [R][C] -> bf16 [C][R] (weights) -------------
__global__ __launch_bounds__(256) void k_transpose_w(const float* __restrict__ in,
                                                     unsigned short* __restrict__ out,
                                                     int R, int C) {
    __shared__ float tile[64][65];
    int c0 = blockIdx.x * 64, r0 = blockIdx.y * 64;
    int t = threadIdx.x;
    int tr = t >> 4, tc = (t & 15) * 4;
#pragma unroll
    for (int p = 0; p < 4; p++) {
        int row = p * 16 + tr;
        float4 v = *(const float4*)(in + (size_t)(r0 + row) * C + c0 + tc);
        tile[row][tc + 0] = v.x; tile[row][tc + 1] = v.y;
        tile[row][tc + 2] = v.z; tile[row][tc + 3] = v.w;
    }
    __syncthreads();
    int oc = t >> 4, orr = (t & 15) * 4;
#pragma unroll
    for (int p = 0; p < 4; p++) {
        int crow = p * 16 + oc;   // original column == output row
        us4 o;
        o.x = f2bf(tile[orr + 0][crow]);
        o.y = f2bf(tile[orr + 1][crow]);
        o.z = f2bf(tile[orr + 2][crow]);
        o.w = f2bf(tile[orr + 3][crow]);
        *(us4*)(out + (size_t)(c0 + crow) * R + r0 + orr) = o;
    }
}

// ---------------- m97-style 128x128 GEMM, BK=64 ----------------
// MODE 0: A = xb [4096][1024], Bt = w1t [3072][1024]; epilogue: +b1,
//   q (scaled by 0.125*log2e) -> qh [B][H][N][DH] bf16,
//   k -> ks fragment-interleaved, v -> vs fragment-interleaved (see k_attn).
// MODE 1: A = attn [B*H][N][DH] (head-strided k), Bt = w2t [1024][1024];
//   epilogue: +b2 -> fp32 out [4096][1024].
template <int MODE>
__global__ __launch_bounds__(256) void k_gemm(const unsigned short* __restrict__ A,
                                              const unsigned short* __restrict__ Bt,
                                              const float* __restrict__ bias,
                                              unsigned short* __restrict__ qdst,
                                              unsigned short* __restrict__ kdst,
                                              unsigned short* __restrict__ vdst,
                                              float* __restrict__ outp) {
    __shared__ unsigned short As[128 * 64];
    __shared__ unsigned short Bs[128 * 64];
    const int K = 1024;
    int tid = threadIdx.x;
    int lane = tid & 63, wv = tid >> 6;
    int wm = wv >> 1, wn = wv & 1;
    int m0 = blockIdx.y * 128;
    int n0 = blockIdx.x * 128;
    int bIdx = m0 >> 11;       // batch index (MODE 1)
    int ntok0 = m0 & 2047;

    f32x4 acc[4][4];
#pragma unroll
    for (int i = 0; i < 4; i++)
#pragma unroll
        for (int j = 0; j < 4; j++) {
            f32x4 z; z[0] = 0.f; z[1] = 0.f; z[2] = 0.f; z[3] = 0.f;
            acc[i][j] = z;
        }

#pragma unroll 1
    for (int k0 = 0; k0 < K; k0 += 64) {
        const unsigned short* aptr;
        int arst;
        if (MODE == 0) { aptr = A + (size_t)m0 * K + k0; arst = K; }
        else {
            int hh = k0 >> 6;
            aptr = A + ((size_t)(bIdx * H_ + hh) * N_ + ntok0) * DH;
            arst = DH;
        }
        const unsigned short* bptr = Bt + (size_t)n0 * K + k0;
#pragma unroll
        for (int i = 0; i < 4; i++) {
            int cidb = i * 256 + wv * 64;          // wave-uniform chunk base
            int cid = cidb + lane;
            load_lds16(aptr + (size_t)(cid >> 3) * arst + (cid & 7) * 8, &As[cidb * 8]);
            load_lds16(bptr + (size_t)(cid >> 3) * K + (cid & 7) * 8, &Bs[cidb * 8]);
        }
        __syncthreads();
#pragma unroll
        for (int kk = 0; kk < 2; ++kk) {
            bf16x8 af[4], bfr[4];
            int ko = kk * 32 + (lane >> 4) * 8;
#pragma unroll
            for (int mi = 0; mi < 4; mi++)
                af[mi] = *(const bf16x8*)&As[(wm * 64 + mi * 16 + (lane & 15)) * 64 + ko];
#pragma unroll
            for (int ni = 0; ni < 4; ni++)
                bfr[ni] = *(const bf16x8*)&Bs[(wn * 64 + ni * 16 + (lane & 15)) * 64 + ko];
#pragma unroll
            for (int mi = 0; mi < 4; mi++)
#pragma unroll
                for (int ni = 0; ni < 4; ni++)
                    acc[mi][ni] = __builtin_amdgcn_mfma_f32_16x16x32_bf16(
                        af[mi], bfr[ni], acc[mi][ni], 0, 0, 0);
        }
        __syncthreads();
    }

    // epilogue  (C/D: col = lane&15, row = (lane>>4)*4 + r)
#pragma unroll
    for (int ni = 0; ni < 4; ni++) {
        int col = n0 + wn * 64 + ni * 16 + (lane & 15);
        float bv = bias[col];
        if (MODE == 0) {
            int which = col >> 10;
            int hd = (col >> 6) & 15;
            int dh = col & 63;
            float scl = (which == 0) ? (0.125f * LOG2E) : 1.0f;
#pragma unroll
            for (int mi = 0; mi < 4; mi++) {
                int rbase = m0 + wm * 64 + mi * 16 + (lane >> 4) * 4;
#pragma unroll
                for (int r = 0; r < 4; r++) {
                    int tok = rbase + r;
                    int bb = tok >> 11, nn = tok & 2047;
                    float vvv = (acc[mi][ni][r] + bv) * scl;
                    size_t chunk = ((size_t)(bb * H_ + hd) * 64 + (nn >> 5)) * 2048;
                    if (which == 0) {
                        qdst[((size_t)(bb * H_ + hd) * N_ + nn) * DH + dh] = f2bf(vvv);
                    } else if (which == 1) {
                        // K fragment-INTERLEAVED: [frag][lane][8el]
                        int lane2 = ((dh >> 3) & 1) * 32 + (nn & 31);
                        kdst[chunk + (dh >> 4) * 512 + lane2 * 8 + (dh & 7)] = f2bf(vvv);
                    } else {
                        // V fragment-INTERLEAVED: [islot][lane][8el]
                        int lane2 = ((nn >> 3) & 1) * 32 + (dh & 31);
                        int islot = (dh >> 5) * 2 + ((nn >> 4) & 1);
                        vdst[chunk + islot * 512 + lane2 * 8 + (nn & 7)] = f2bf(vvv);
                    }
                }
            }
        } else {
#pragma unroll
            for (int mi = 0; mi < 4; mi++) {
                int rbase = m0 + wm * 64 + mi * 16 + (lane >> 4) * 4;
#pragma unroll
                for (int r = 0; r < 4; r++)
                    outp[(size_t)(rbase + r) * D_ + col] = acc[mi][ni][r] + bv;
            }
        }
    }
}

// ---------------- flash attention, LDS-staged K/V, 8 waves, KVBLK=64 ----------------
// qh: [B][H][N][DH] bf16 (scaled 0.125*log2e); ks, vs: fragment-interleaved
//   per-32kv chunk = 2048 el: frag*512 + lane*8 + elem (linear per 64-kv tile: 4096 el).
// o: [B*H][N][DH] bf16
// Block: 512 threads = 8 waves; wave w owns q-rows [q0+w*32, +32); full 2048-kv sweep.
// K/V double-buffered in LDS via global_load_lds (linear dest), 1 barrier/tile.
__global__ __launch_bounds__(512, 2) void k_attn(const unsigned short* __restrict__ qh,
                                                 const unsigned short* __restrict__ ks,
                                                 const unsigned short* __restrict__ vs,
                                                 unsigned short* __restrict__ o) {
    __shared__ unsigned short kbuf[2][4096];
    __shared__ unsigned short vbuf[2][4096];
    int tid = threadIdx.x;
    int lane = tid & 63, wv = tid >> 6;      // wv 0..7
    // XCD swizzle: 256 blocks, XCD x gets logical L in [x*32,(x+1)*32) => bh in [4x,4x+4)
    int F = blockIdx.x;
    int L = (F & 7) * 32 + (F >> 3);
    int bh = L >> 3;
    int q0 = (L & 7) * 256 + wv * 32;
    int ln = lane & 31, hi = lane >> 5;
    const size_t bhO = (size_t)bh * N_ * DH;

    // Q fragments (B operand of mfma(K,Q)): lane owns q-row = ln
    const unsigned short* qp = qh + bhO;
    bf16x8 qf[4];
#pragma unroll
    for (int kk = 0; kk < 4; kk++)
        qf[kk] = *(const bf16x8*)(qp + (size_t)(q0 + ln) * DH + kk * 16 + hi * 8);

    const unsigned short* kg = ks + (size_t)bh * 131072;
    const unsigned short* vg = vs + (size_t)bh * 131072;

    f32x16 o0, o1;
#pragma unroll
    for (int r = 0; r < 16; r++) { o0[r] = 0.f; o1[r] = 0.f; }
    float m = -INFINITY, l = 0.f;

    // stage tile 0 (64 kv = 4096 el of K and of V; each wave stages its 1KB slice)
    load_lds16(kg + wv * 512 + lane * 8, &kbuf[0][wv * 512]);
    load_lds16(vg + wv * 512 + lane * 8, &vbuf[0][wv * 512]);
    __syncthreads();

#pragma unroll 1
    for (int t = 0; t < 32; ++t) {
        int b = t & 1;
        if (t < 31) {
            load_lds16(kg + (size_t)(t + 1) * 4096 + wv * 512 + lane * 8, &kbuf[b ^ 1][wv * 512]);
            load_lds16(vg + (size_t)(t + 1) * 4096 + wv * 512 + lane * 8, &vbuf[b ^ 1][wv * 512]);
        }

        // ---- QK^T: two independent 4-MFMA chains (kv chunks c0, c1) ----
        bf16x8 kfa[4], kfb[4];
#pragma unroll
        for (int i = 0; i < 4; i++) {
            kfa[i] = *(const bf16x8*)&kbuf[b][i * 512 + lane * 8];
            kfb[i] = *(const bf16x8*)&kbuf[b][2048 + i * 512 + lane * 8];
        }
        f32x16 sa, sb;
#pragma unroll
        for (int r = 0; r < 16; r++) { sa[r] = 0.f; sb[r] = 0.f; }
#pragma unroll
        for (int i = 0; i < 4; i++)
            sa = __builtin_amdgcn_mfma_f32_32x32x16_bf16(kfa[i], qf[i], sa, 0, 0, 0);
#pragma unroll
        for (int i = 0; i < 4; i++)
            sb = __builtin_amdgcn_mfma_f32_32x32x16_bf16(kfb[i], qf[i], sb, 0, 0, 0);
        // s[r] = S^T[kv][q] (log2 domain): q = ln, kv = (r&3)+8*(r>>2)+4*hi (+32 for sb)

        // ---- online softmax over 64 kv ----
        float mx[8];
#pragma unroll
        for (int i = 0; i < 8; i++)
            mx[i] = fmaxf(fmaxf(sa[i], sa[i + 8]), fmaxf(sb[i], sb[i + 8]));
#pragma unroll
        for (int i = 0; i < 4; i++) mx[i] = fmaxf(mx[i], mx[i + 4]);
        float mt = fmaxf(fmaxf(mx[0], mx[2]), fmaxf(mx[1], mx[3]));
        {   // cross-half (lane ^ 32) via permlane32_swap (VALU, no LDS)
            u32x2 sw = __builtin_amdgcn_permlane32_swap(f2u(mt), f2u(mt), false, false);
            mt = fmaxf(u2f(sw[0]), u2f(sw[1]));
        }
        if (!__all(mt <= m + 8.0f)) {   // defer-max, exp2 domain (p <= 2^8)
            float mn = fmaxf(m, mt);
            float fs = __builtin_amdgcn_exp2f(m - mn);
            m = mn;
            l *= fs;
#pragma unroll
            for (int r = 0; r < 16; r++) { o0[r] *= fs; o1[r] *= fs; }
        }
        float pa[16], pb[16];
#pragma unroll
        for (int r = 0; r < 16; r++) {
            pa[r] = __builtin_amdgcn_exp2f(sa[r] - m);
            pb[r] = __builtin_amdgcn_exp2f(sb[r] - m);
        }
        float sm[8];
#pragma unroll
        for (int i = 0; i < 8; i++) sm[i] = (pa[i] + pa[i + 8]) + (pb[i] + pb[i + 8]);
#pragma unroll
        for (int i = 0; i < 4; i++) sm[i] = sm[i] + sm[i + 4];
        float sum = (sm[0] + sm[2]) + (sm[1] + sm[3]);
        {
            u32x2 sw = __builtin_amdgcn_permlane32_swap(f2u(sum), f2u(sum), false, false);
            sum = u2f(sw[0]) + u2f(sw[1]);
        }
        l += sum;

        // ---- pack P -> bf16 PV B-operands (verified wiring) ----
        unsigned pka[8], pkb[8];
#pragma unroll
        for (int i = 0; i < 8; i++) {
            pka[i] = cvt_pk_bf16(pa[2 * i], pa[2 * i + 1]);
            pkb[i] = cvt_pk_bf16(pb[2 * i], pb[2 * i + 1]);
        }
        u32x2 s0 = __builtin_amdgcn_permlane32_swap(pka[0], pka[2], false, false);
        u32x2 s1 = __builtin_amdgcn_permlane32_swap(pka[1], pka[3], false, false);
        u32x2 s2 = __builtin_amdgcn_permlane32_swap(pka[4], pka[6], false, false);
        u32x2 s3 = __builtin_amdgcn_permlane32_swap(pka[5], pka[7], false, false);
        bf16x8 pf0 = frag_from_u32(s0[0], s1[0], s0[1], s1[1]);  // kv  0..15
        bf16x8 pf1 = frag_from_u32(s2[0], s3[0], s2[1], s3[1]);  // kv 16..31
        s0 = __builtin_amdgcn_permlane32_swap(pkb[0], pkb[2], false, false);
        s1 = __builtin_amdgcn_permlane32_swap(pkb[1], pkb[3], false, false);
        s2 = __builtin_amdgcn_permlane32_swap(pkb[4], pkb[6], false, false);
        s3 = __builtin_amdgcn_permlane32_swap(pkb[5], pkb[7], false, false);
        bf16x8 pf2 = frag_from_u32(s0[0], s1[0], s0[1], s1[1]);  // kv 32..47
        bf16x8 pf3 = frag_from_u32(s2[0], s3[0], s2[1], s3[1]);  // kv 48..63

        // ---- PV: O^T[d][q] += V^T[d][kv] * P^T[kv][q] ----
        bf16x8 vf0, vf1, vf2, vf3;
        vf0 = *(const bf16x8*)&vbuf[b][0 * 512 + lane * 8];          // c0, d 0..31, kv 0..15
        vf1 = *(const bf16x8*)&vbuf[b][1 * 512 + lane * 8];          // c0, d 0..31, kv16..31
        vf2 = *(const bf16x8*)&vbuf[b][2048 + 0 * 512 + lane * 8];   // c1, d 0..31, kv32..47
        vf3 = *(const bf16x8*)&vbuf[b][2048 + 1 * 512 + lane * 8];   // c1, d 0..31, kv48..63
        o0 = __builtin_amdgcn_mfma_f32_32x32x16_bf16(vf0, pf0, o0, 0, 0, 0);
        o0 = __builtin_amdgcn_mfma_f32_32x32x16_bf16(vf1, pf1, o0, 0, 0, 0);
        o0 = __builtin_amdgcn_mfma_f32_32x32x16_bf16(vf2, pf2, o0, 0, 0, 0);
        o0 = __builtin_amdgcn_mfma_f32_32x32x16_bf16(vf3, pf3, o0, 0, 0, 0);
        vf0 = *(const bf16x8*)&vbuf[b][2 * 512 + lane * 8];          // c0, d32..63, kv 0..15
        vf1 = *(const bf16x8*)&vbuf[b][3 * 512 + lane * 8];          // c0, d32..63, kv16..31
        vf2 = *(const bf16x8*)&vbuf[b][2048 + 2 * 512 + lane * 8];   // c1, d32..63, kv32..47
        vf3 = *(const bf16x8*)&vbuf[b][2048 + 3 * 512 + lane * 8];   // c1, d32..63, kv48..63
        o1 = __builtin_amdgcn_mfma_f32_32x32x16_bf16(vf0, pf0, o1, 0, 0, 0);
        o1 = __builtin_amdgcn_mfma_f32_32x32x16_bf16(vf1, pf1, o1, 0, 0, 0);
        o1 = __builtin_amdgcn_mfma_f32_32x32x16_bf16(vf2, pf2, o1, 0, 0, 0);
        o1 = __builtin_amdgcn_mfma_f32_32x32x16_bf16(vf3, pf3, o1, 0, 0, 0);

        __syncthreads();   // stage(t+1) landed (vmcnt drain) + all reads of buf[b] done
    }

    // epilogue: each wave owns its 32 q-rows fully
    float inv = 1.0f / l;
    unsigned short* ob = o + bhO + (size_t)(q0 + ln) * DH;
#pragma unroll
    for (int t2 = 0; t2 < 2; t2++) {
#pragma unroll
        for (int g = 0; g < 4; g++) {
            int d = t2 * 32 + g * 8 + hi * 4;   // rows: (r&3)+8*(r>>2)+4*hi
            int rb = g * 4;
            float a0 = (t2 ? o1[rb + 0] : o0[rb + 0]) * inv;
            float a1 = (t2 ? o1[rb + 1] : o0[rb + 1]) * inv;
            float a2 = (t2 ? o1[rb + 2] : o0[rb + 2]) * inv;
            float a3 = (t2 ? o1[rb + 3] : o0[rb + 3]) * inv;
            us4 w;
            w.x = f2bf(a0); w.y = f2bf(a1); w.z = f2bf(a2); w.w = f2bf(a3);
            *(us4*)(ob + d) = w;
        }
    }
}

extern "C" void kernel_launch(void* const* d_in, const int* in_sizes, int n_in,
                              void* d_out, int out_size, void* d_ws, size_t ws_size,
                              hipStream_t stream) {
    const float* x  = (const float*)d_in[0];
    const float* W1 = (const float*)d_in[1];
    const float* b1 = (const float*)d_in[2];
    const float* W2 = (const float*)d_in[3];
    const float* b2 = (const float*)d_in[4];
    float* out = (float*)d_out;

    char* ws = (char*)d_ws;
    unsigned short* xb   = (unsigned short*)(ws);                  //  8,388,608 B
    unsigned short* w1t  = (unsigned short*)(ws + 8388608);        //  6,291,456 B
    unsigned short* w2t  = (unsigned short*)(ws + 14680064);       //  2,097,152 B
    unsigned short* qh   = (unsigned short*)(ws + 16777216);       //  8,388,608 B
    unsigned short* ks   = (unsigned short*)(ws + 25165824);       //  8,388,608 B
    unsigned short* vsb  = (unsigned short*)(ws + 33554432);       //  8,388,608 B
    unsigned short* attn = (unsigned short*)(ws + 41943040);       //  8,388,608 B

    k_cvt_x<<<4096, 256, 0, stream>>>(x, xb, MTOK * D_);
    k_transpose_w<<<dim3(48, 16), 256, 0, stream>>>(W1, w1t, D_, 3 * D_);
    k_transpose_w<<<dim3(16, 16), 256, 0, stream>>>(W2, w2t, D_, D_);
    k_gemm<0><<<dim3(24, 32), 256, 0, stream>>>(xb, w1t, b1, qh, ks, vsb, nullptr);
    k_attn<<<256, 512, 0, stream>>>(qh, ks, vsb, attn);
    k_gemm<1><<<dim3(8, 32), 256, 0, stream>>>(attn, w2t, b2, nullptr, nullptr, nullptr, out);
}

// Round 7
// 146.971 us; speedup vs baseline: 1.6196x; 1.0140x over previous
//
#include <hip/hip_runtime.h>
#include <hip/hip_bf16.h>
#include <stdint.h>

// Problem constants
#define B_   2
#define H_   16
#define N_   2048
#define D_   1024
#define DH   64
#define MTOK 4096   // B_*N_

#define LOG2E 1.44269504088896f

typedef __attribute__((ext_vector_type(8)))  short bf16x8;
typedef __attribute__((ext_vector_type(4)))  float f32x4;
typedef __attribute__((ext_vector_type(16))) float f32x16;
typedef __attribute__((ext_vector_type(2)))  unsigned u32x2;
typedef __attribute__((ext_vector_type(4)))  unsigned short us4;

static __device__ __forceinline__ unsigned short f2bf(float f) {
    union { float f; unsigned u; } v; v.f = f;
    unsigned r = v.u + 0x7fffu + ((v.u >> 16) & 1u);
    return (unsigned short)(r >> 16);
}

static __device__ __forceinline__ unsigned f2u(float x) {
    union { float f; unsigned u; } v; v.f = x; return v.u;
}
static __device__ __forceinline__ float u2f(unsigned x) {
    union { unsigned u; float f; } v; v.u = x; return v.f;
}

static __device__ __forceinline__ unsigned cvt_pk_bf16(float lo, float hi) {
    unsigned r;
    asm("v_cvt_pk_bf16_f32 %0, %1, %2" : "=v"(r) : "v"(lo), "v"(hi));
    return r;
}

static __device__ __forceinline__ bf16x8 frag_from_u32(unsigned a, unsigned b, unsigned c, unsigned d) {
    union { unsigned u[4]; bf16x8 v; } x;
    x.u[0] = a; x.u[1] = b; x.u[2] = c; x.u[3] = d;
    return x.v;
}

static __device__ __forceinline__ void load_lds16(const void* g, void* l) {
    __builtin_amdgcn_global_load_lds(
        (const __attribute__((address_space(1))) unsigned int*)g,
        (__attribute__((address_space(3))) unsigned int*)l, 16, 0, 0);
}

// ---------------- fp32 -> bf16 elementwise (x) ----------------
__global__ __launch_bounds__(256) void k_cvt_x(const float* __restrict__ x,
                                               unsigned short* __restrict__ xb, int n) {
    int idx = (blockIdx.x * 256 + threadIdx.x) * 4;
    if (idx < n) {
        float4 v = *(const float4*)(x + idx);
        us4 o;
        o.x = f2bf(v.x); o.y = f2bf(v.y); o.z = f2bf(v.z); o.w = f2bf(v.w);
        *(us4*)(xb + idx) = o;
    }
}

// ------------- fp32 [R][C] -> bf16 [C][R] (weights) -------------
__global__ __launch_bounds__(256) void k_transpose_w(const float* __restrict__ in,
                                                     unsigned short* __restrict__ out,
                                                     int R, int C) {
    __shared__ float tile[64][65];
    int c0 = blockIdx.x * 64, r0 = blockIdx.y * 64;
    int t = threadIdx.x;
    int tr = t >> 4, tc = (t & 15) * 4;
#pragma unroll
    for (int p = 0; p < 4; p++) {
        int row = p * 16 + tr;
        float4 v = *(const float4*)(in + (size_t)(r0 + row) * C + c0 + tc);
        tile[row][tc + 0] = v.x; tile[row][tc + 1] = v.y;
        tile[row][tc + 2] = v.z; tile[row][tc + 3] = v.w;
    }
    __syncthreads();
    int oc = t >> 4, orr = (t & 15) * 4;
#pragma unroll
    for (int p = 0; p < 4; p++) {
        int crow = p * 16 + oc;   // original column == output row
        us4 o;
        o.x = f2bf(tile[orr + 0][crow]);
        o.y = f2bf(tile[orr + 1][crow]);
        o.z = f2bf(tile[orr + 2][crow]);
        o.w = f2bf(tile[orr + 3][crow]);
        *(us4*)(out + (size_t)(c0 + crow) * R + r0 + orr) = o;
    }
}

// -------- 128x128 GEMM, BK=64, 2-phase double-buffered + XCD swizzle --------
// MODE 0: A = xb [4096][1024], Bt = w1t [3072][1024]; epilogue: +b1,
//   q (scaled by 0.125*log2e) -> qh [B][H][N][DH] bf16,
//   k -> ks fragment-interleaved, v -> vs fragment-interleaved (see k_attn).
// MODE 1: A = attn [B*H][N][DH] (head-strided k), Bt = w2t [1024][1024];
//   epilogue: +b2 -> fp32 out [4096][1024].
template <int MODE>
__global__ __launch_bounds__(256) void k_gemm(const unsigned short* __restrict__ A,
                                              const unsigned short* __restrict__ Bt,
                                              const float* __restrict__ bias,
                                              unsigned short* __restrict__ qdst,
                                              unsigned short* __restrict__ kdst,
                                              unsigned short* __restrict__ vdst,
                                              float* __restrict__ outp) {
    __shared__ unsigned short As[2][128 * 64];
    __shared__ unsigned short Bs[2][128 * 64];
    const int K = 1024;
    int tid = threadIdx.x;
    int lane = tid & 63, wv = tid >> 6;
    int wm = wv >> 1, wn = wv & 1;

    // flat grid + bijective XCD swizzle (nwg % 8 == 0)
    const int NX  = (MODE == 0) ? 24 : 8;        // n-tiles
    const int CPX = (MODE == 0) ? 96 : 32;       // nwg/8
    int F = blockIdx.x;
    int L = (F & 7) * CPX + (F >> 3);
    int n0 = (L % NX) * 128;
    int m0 = (L / NX) * 128;
    int bIdx = m0 >> 11;       // batch index (MODE 1)
    int ntok0 = m0 & 2047;

    f32x4 acc[4][4];
#pragma unroll
    for (int i = 0; i < 4; i++)
#pragma unroll
        for (int j = 0; j < 4; j++) {
            f32x4 z; z[0] = 0.f; z[1] = 0.f; z[2] = 0.f; z[3] = 0.f;
            acc[i][j] = z;
        }

    auto stage = [&](int buf, int k0) {
        const unsigned short* aptr;
        int arst;
        if (MODE == 0) { aptr = A + (size_t)m0 * K + k0; arst = K; }
        else {
            int hh = k0 >> 6;
            aptr = A + ((size_t)(bIdx * H_ + hh) * N_ + ntok0) * DH;
            arst = DH;
        }
        const unsigned short* bptr = Bt + (size_t)n0 * K + k0;
#pragma unroll
        for (int i = 0; i < 4; i++) {
            int cidb = i * 256 + wv * 64;          // wave-uniform chunk base
            int cid = cidb + lane;
            load_lds16(aptr + (size_t)(cid >> 3) * arst + (cid & 7) * 8, &As[buf][cidb * 8]);
            load_lds16(bptr + (size_t)(cid >> 3) * K + (cid & 7) * 8, &Bs[buf][cidb * 8]);
        }
    };

    stage(0, 0);
    __syncthreads();   // vmcnt(0) drain: tile 0 landed

#pragma unroll 1
    for (int t = 0; t < 16; ++t) {
        int cur = t & 1;
        if (t < 15) stage(cur ^ 1, (t + 1) * 64);   // prefetch next tile (in flight during MFMA)
#pragma unroll
        for (int kk = 0; kk < 2; ++kk) {
            bf16x8 af[4], bfr[4];
            int ko = kk * 32 + (lane >> 4) * 8;
#pragma unroll
            for (int mi = 0; mi < 4; mi++)
                af[mi] = *(const bf16x8*)&As[cur][(wm * 64 + mi * 16 + (lane & 15)) * 64 + ko];
#pragma unroll
            for (int ni = 0; ni < 4; ni++)
                bfr[ni] = *(const bf16x8*)&Bs[cur][(wn * 64 + ni * 16 + (lane & 15)) * 64 + ko];
#pragma unroll
            for (int mi = 0; mi < 4; mi++)
#pragma unroll
                for (int ni = 0; ni < 4; ni++)
                    acc[mi][ni] = __builtin_amdgcn_mfma_f32_16x16x32_bf16(
                        af[mi], bfr[ni], acc[mi][ni], 0, 0, 0);
        }
        __syncthreads();   // one barrier/step: next tile landed + cur-buf reads done
    }

    // epilogue  (C/D: col = lane&15, row = (lane>>4)*4 + r)
#pragma unroll
    for (int ni = 0; ni < 4; ni++) {
        int col = n0 + wn * 64 + ni * 16 + (lane & 15);
        float bv = bias[col];
        if (MODE == 0) {
            int which = col >> 10;
            int hd = (col >> 6) & 15;
            int dh = col & 63;
            float scl = (which == 0) ? (0.125f * LOG2E) : 1.0f;
#pragma unroll
            for (int mi = 0; mi < 4; mi++) {
                int rbase = m0 + wm * 64 + mi * 16 + (lane >> 4) * 4;
#pragma unroll
                for (int r = 0; r < 4; r++) {
                    int tok = rbase + r;
                    int bb = tok >> 11, nn = tok & 2047;
                    float vvv = (acc[mi][ni][r] + bv) * scl;
                    size_t chunk = ((size_t)(bb * H_ + hd) * 64 + (nn >> 5)) * 2048;
                    if (which == 0) {
                        qdst[((size_t)(bb * H_ + hd) * N_ + nn) * DH + dh] = f2bf(vvv);
                    } else if (which == 1) {
                        // K fragment-INTERLEAVED: [frag][lane][8el]
                        int lane2 = ((dh >> 3) & 1) * 32 + (nn & 31);
                        kdst[chunk + (dh >> 4) * 512 + lane2 * 8 + (dh & 7)] = f2bf(vvv);
                    } else {
                        // V fragment-INTERLEAVED: [islot][lane][8el]
                        int lane2 = ((nn >> 3) & 1) * 32 + (dh & 31);
                        int islot = (dh >> 5) * 2 + ((nn >> 4) & 1);
                        vdst[chunk + islot * 512 + lane2 * 8 + (nn & 7)] = f2bf(vvv);
                    }
                }
            }
        } else {
#pragma unroll
            for (int mi = 0; mi < 4; mi++) {
                int rbase = m0 + wm * 64 + mi * 16 + (lane >> 4) * 4;
#pragma unroll
                for (int r = 0; r < 4; r++)
                    outp[(size_t)(rbase + r) * D_ + col] = acc[mi][ni][r] + bv;
            }
        }
    }
}

// ---------------- flash attention, LDS-staged K/V, 8 waves, KVBLK=64 ----------------
// qh: [B][H][N][DH] bf16 (scaled 0.125*log2e); ks, vs: fragment-interleaved
//   per-32kv chunk = 2048 el: frag*512 + lane*8 + elem (linear per 64-kv tile: 4096 el).
// o: [B*H][N][DH] bf16
__global__ __launch_bounds__(512, 2) void k_attn(const unsigned short* __restrict__ qh,
                                                 const unsigned short* __restrict__ ks,
                                                 const unsigned short* __restrict__ vs,
                                                 unsigned short* __restrict__ o) {
    __shared__ unsigned short kbuf[2][4096];
    __shared__ unsigned short vbuf[2][4096];
    int tid = threadIdx.x;
    int lane = tid & 63, wv = tid >> 6;      // wv 0..7
    // XCD swizzle: 256 blocks, XCD x gets logical L in [x*32,(x+1)*32) => bh in [4x,4x+4)
    int F = blockIdx.x;
    int L = (F & 7) * 32 + (F >> 3);
    int bh = L >> 3;
    int q0 = (L & 7) * 256 + wv * 32;
    int ln = lane & 31, hi = lane >> 5;
    const size_t bhO = (size_t)bh * N_ * DH;

    // Q fragments (B operand of mfma(K,Q)): lane owns q-row = ln
    const unsigned short* qp = qh + bhO;
    bf16x8 qf[4];
#pragma unroll
    for (int kk = 0; kk < 4; kk++)
        qf[kk] = *(const bf16x8*)(qp + (size_t)(q0 + ln) * DH + kk * 16 + hi * 8);

    const unsigned short* kg = ks + (size_t)bh * 131072;
    const unsigned short* vg = vs + (size_t)bh * 131072;

    f32x16 o0, o1;
#pragma unroll
    for (int r = 0; r < 16; r++) { o0[r] = 0.f; o1[r] = 0.f; }
    float m = -INFINITY, l = 0.f;

    // stage tile 0 (64 kv = 4096 el of K and of V; each wave stages its 1KB slice)
    load_lds16(kg + wv * 512 + lane * 8, &kbuf[0][wv * 512]);
    load_lds16(vg + wv * 512 + lane * 8, &vbuf[0][wv * 512]);
    __syncthreads();

#pragma unroll 1
    for (int t = 0; t < 32; ++t) {
        int b = t & 1;
        if (t < 31) {
            load_lds16(kg + (size_t)(t + 1) * 4096 + wv * 512 + lane * 8, &kbuf[b ^ 1][wv * 512]);
            load_lds16(vg + (size_t)(t + 1) * 4096 + wv * 512 + lane * 8, &vbuf[b ^ 1][wv * 512]);
        }

        // ---- QK^T: two independent 4-MFMA chains (kv chunks c0, c1) ----
        bf16x8 kfa[4], kfb[4];
#pragma unroll
        for (int i = 0; i < 4; i++) {
            kfa[i] = *(const bf16x8*)&kbuf[b][i * 512 + lane * 8];
            kfb[i] = *(const bf16x8*)&kbuf[b][2048 + i * 512 + lane * 8];
        }
        f32x16 sa, sb;
#pragma unroll
        for (int r = 0; r < 16; r++) { sa[r] = 0.f; sb[r] = 0.f; }
#pragma unroll
        for (int i = 0; i < 4; i++)
            sa = __builtin_amdgcn_mfma_f32_32x32x16_bf16(kfa[i], qf[i], sa, 0, 0, 0);
#pragma unroll
        for (int i = 0; i < 4; i++)
            sb = __builtin_amdgcn_mfma_f32_32x32x16_bf16(kfb[i], qf[i], sb, 0, 0, 0);
        // s[r] = S^T[kv][q] (log2 domain): q = ln, kv = (r&3)+8*(r>>2)+4*hi (+32 for sb)

        // ---- online softmax over 64 kv ----
        float mx[8];
#pragma unroll
        for (int i = 0; i < 8; i++)
            mx[i] = fmaxf(fmaxf(sa[i], sa[i + 8]), fmaxf(sb[i], sb[i + 8]));
#pragma unroll
        for (int i = 0; i < 4; i++) mx[i] = fmaxf(mx[i], mx[i + 4]);
        float mt = fmaxf(fmaxf(mx[0], mx[2]), fmaxf(mx[1], mx[3]));
        {   // cross-half (lane ^ 32) via permlane32_swap (VALU, no LDS)
            u32x2 sw = __builtin_amdgcn_permlane32_swap(f2u(mt), f2u(mt), false, false);
            mt = fmaxf(u2f(sw[0]), u2f(sw[1]));
        }
        if (!__all(mt <= m + 8.0f)) {   // defer-max, exp2 domain (p <= 2^8)
            float mn = fmaxf(m, mt);
            float fs = __builtin_amdgcn_exp2f(m - mn);
            m = mn;
            l *= fs;
#pragma unroll
            for (int r = 0; r < 16; r++) { o0[r] *= fs; o1[r] *= fs; }
        }
        float pa[16], pb[16];
#pragma unroll
        for (int r = 0; r < 16; r++) {
            pa[r] = __builtin_amdgcn_exp2f(sa[r] - m);
            pb[r] = __builtin_amdgcn_exp2f(sb[r] - m);
        }
        float sm[8];
#pragma unroll
        for (int i = 0; i < 8; i++) sm[i] = (pa[i] + pa[i + 8]) + (pb[i] + pb[i + 8]);
#pragma unroll
        for (int i = 0; i < 4; i++) sm[i] = sm[i] + sm[i + 4];
        float sum = (sm[0] + sm[2]) + (sm[1] + sm[3]);
        {
            u32x2 sw = __builtin_amdgcn_permlane32_swap(f2u(sum), f2u(sum), false, false);
            sum = u2f(sw[0]) + u2f(sw[1]);
        }
        l += sum;

        // ---- pack P -> bf16 PV B-operands (verified wiring) ----
        unsigned pka[8], pkb[8];
#pragma unroll
        for (int i = 0; i < 8; i++) {
            pka[i] = cvt_pk_bf16(pa[2 * i], pa[2 * i + 1]);
            pkb[i] = cvt_pk_bf16(pb[2 * i], pb[2 * i + 1]);
        }
        u32x2 s0 = __builtin_amdgcn_permlane32_swap(pka[0], pka[2], false, false);
        u32x2 s1 = __builtin_amdgcn_permlane32_swap(pka[1], pka[3], false, false);
        u32x2 s2 = __builtin_amdgcn_permlane32_swap(pka[4], pka[6], false, false);
        u32x2 s3 = __builtin_amdgcn_permlane32_swap(pka[5], pka[7], false, false);
        bf16x8 pf0 = frag_from_u32(s0[0], s1[0], s0[1], s1[1]);  // kv  0..15
        bf16x8 pf1 = frag_from_u32(s2[0], s3[0], s2[1], s3[1]);  // kv 16..31
        s0 = __builtin_amdgcn_permlane32_swap(pkb[0], pkb[2], false, false);
        s1 = __builtin_amdgcn_permlane32_swap(pkb[1], pkb[3], false, false);
        s2 = __builtin_amdgcn_permlane32_swap(pkb[4], pkb[6], false, false);
        s3 = __builtin_amdgcn_permlane32_swap(pkb[5], pkb[7], false, false);
        bf16x8 pf2 = frag_from_u32(s0[0], s1[0], s0[1], s1[1]);  // kv 32..47
        bf16x8 pf3 = frag_from_u32(s2[0], s3[0], s2[1], s3[1]);  // kv 48..63

        // ---- PV: O^T[d][q] += V^T[d][kv] * P^T[kv][q] ----
        bf16x8 vf0, vf1, vf2, vf3;
        vf0 = *(const bf16x8*)&vbuf[b][0 * 512 + lane * 8];          // c0, d 0..31, kv 0..15
        vf1 = *(const bf16x8*)&vbuf[b][1 * 512 + lane * 8];          // c0, d 0..31, kv16..31
        vf2 = *(const bf16x8*)&vbuf[b][2048 + 0 * 512 + lane * 8];   // c1, d 0..31, kv32..47
        vf3 = *(const bf16x8*)&vbuf[b][2048 + 1 * 512 + lane * 8];   // c1, d 0..31, kv48..63
        o0 = __builtin_amdgcn_mfma_f32_32x32x16_bf16(vf0, pf0, o0, 0, 0, 0);
        o0 = __builtin_amdgcn_mfma_f32_32x32x16_bf16(vf1, pf1, o0, 0, 0, 0);
        o0 = __builtin_amdgcn_mfma_f32_32x32x16_bf16(vf2, pf2, o0, 0, 0, 0);
        o0 = __builtin_amdgcn_mfma_f32_32x32x16_bf16(vf3, pf3, o0, 0, 0, 0);
        vf0 = *(const bf16x8*)&vbuf[b][2 * 512 + lane * 8];          // c0, d32..63, kv 0..15
        vf1 = *(const bf16x8*)&vbuf[b][3 * 512 + lane * 8];          // c0, d32..63, kv16..31
        vf2 = *(const bf16x8*)&vbuf[b][2048 + 2 * 512 + lane * 8];   // c1, d32..63, kv32..47
        vf3 = *(const bf16x8*)&vbuf[b][2048 + 3 * 512 + lane * 8];   // c1, d32..63, kv48..63
        o1 = __builtin_amdgcn_mfma_f32_32x32x16_bf16(vf0, pf0, o1, 0, 0, 0);
        o1 = __builtin_amdgcn_mfma_f32_32x32x16_bf16(vf1, pf1, o1, 0, 0, 0);
        o1 = __builtin_amdgcn_mfma_f32_32x32x16_bf16(vf2, pf2, o1, 0, 0, 0);
        o1 = __builtin_amdgcn_mfma_f32_32x32x16_bf16(vf3, pf3, o1, 0, 0, 0);

        __syncthreads();   // stage(t+1) landed (vmcnt drain) + all reads of buf[b] done
    }

    // epilogue: each wave owns its 32 q-rows fully
    float inv = 1.0f / l;
    unsigned short* ob = o + bhO + (size_t)(q0 + ln) * DH;
#pragma unroll
    for (int t2 = 0; t2 < 2; t2++) {
#pragma unroll
        for (int g = 0; g < 4; g++) {
            int d = t2 * 32 + g * 8 + hi * 4;   // rows: (r&3)+8*(r>>2)+4*hi
            int rb = g * 4;
            float a0 = (t2 ? o1[rb + 0] : o0[rb + 0]) * inv;
            float a1 = (t2 ? o1[rb + 1] : o0[rb + 1]) * inv;
            float a2 = (t2 ? o1[rb + 2] : o0[rb + 2]) * inv;
            float a3 = (t2 ? o1[rb + 3] : o0[rb + 3]) * inv;
            us4 w;
            w.x = f2bf(a0); w.y = f2bf(a1); w.z = f2bf(a2); w.w = f2bf(a3);
            *(us4*)(ob + d) = w;
        }
    }
}

extern "C" void kernel_launch(void* const* d_in, const int* in_sizes, int n_in,
                              void* d_out, int out_size, void* d_ws, size_t ws_size,
                              hipStream_t stream) {
    const float* x  = (const float*)d_in[0];
    const float* W1 = (const float*)d_in[1];
    const float* b1 = (const float*)d_in[2];
    const float* W2 = (const float*)d_in[3];
    const float* b2 = (const float*)d_in[4];
    float* out = (float*)d_out;

    char* ws = (char*)d_ws;
    unsigned short* xb   = (unsigned short*)(ws);                  //  8,388,608 B
    unsigned short* w1t  = (unsigned short*)(ws + 8388608);        //  6,291,456 B
    unsigned short* w2t  = (unsigned short*)(ws + 14680064);       //  2,097,152 B
    unsigned short* qh   = (unsigned short*)(ws + 16777216);       //  8,388,608 B
    unsigned short* ks   = (unsigned short*)(ws + 25165824);       //  8,388,608 B
    unsigned short* vsb  = (unsigned short*)(ws + 33554432);       //  8,388,608 B
    unsigned short* attn = (unsigned short*)(ws + 41943040);       //  8,388,608 B

    k_cvt_x<<<4096, 256, 0, stream>>>(x, xb, MTOK * D_);
    k_transpose_w<<<dim3(48, 16), 256, 0, stream>>>(W1, w1t, D_, 3 * D_);
    k_transpose_w<<<dim3(16, 16), 256, 0, stream>>>(W2, w2t, D_, D_);
    k_gemm<0><<<768, 256, 0, stream>>>(xb, w1t, b1, qh, ks, vsb, nullptr);
    k_attn<<<256, 512, 0, stream>>>(qh, ks, vsb, attn);
    k_gemm<1><<<256, 256, 0, stream>>>(attn, w2t, b2, nullptr, nullptr, nullptr, out);
}

// Round 8
// 144.171 us; speedup vs baseline: 1.6510x; 1.0194x over previous
//
#include <hip/hip_runtime.h>
#include <hip/hip_bf16.h>
#include <stdint.h>

// Problem constants
#define B_   2
#define H_   16
#define N_   2048
#define D_   1024
#define DH   64
#define MTOK 4096   // B_*N_

#define LOG2E 1.44269504088896f

typedef __attribute__((ext_vector_type(8)))  short bf16x8;
typedef __attribute__((ext_vector_type(4)))  float f32x4;
typedef __attribute__((ext_vector_type(16))) float f32x16;
typedef __attribute__((ext_vector_type(2)))  unsigned u32x2;
typedef __attribute__((ext_vector_type(4)))  unsigned short us4;

#define VMCNT_ASM(N) asm volatile("s_waitcnt vmcnt(" #N ")" ::: "memory")

static __device__ __forceinline__ unsigned short f2bf(float f) {
    union { float f; unsigned u; } v; v.f = f;
    unsigned r = v.u + 0x7fffu + ((v.u >> 16) & 1u);
    return (unsigned short)(r >> 16);
}

static __device__ __forceinline__ unsigned f2u(float x) {
    union { float f; unsigned u; } v; v.f = x; return v.u;
}
static __device__ __forceinline__ float u2f(unsigned x) {
    union { unsigned u; float f; } v; v.u = x; return v.f;
}

static __device__ __forceinline__ unsigned cvt_pk_bf16(float lo, float hi) {
    unsigned r;
    asm("v_cvt_pk_bf16_f32 %0, %1, %2" : "=v"(r) : "v"(lo), "v"(hi));
    return r;
}

static __device__ __forceinline__ bf16x8 frag_from_u32(unsigned a, unsigned b, unsigned c, unsigned d) {
    union { unsigned u[4]; bf16x8 v; } x;
    x.u[0] = a; x.u[1] = b; x.u[2] = c; x.u[3] = d;
    return x.v;
}

static __device__ __forceinline__ void load_lds16(const void* g, void* l) {
    __builtin_amdgcn_global_load_lds(
        (const __attribute__((address_space(1))) unsigned int*)g,
        (__attribute__((address_space(3))) unsigned int*)l, 16, 0, 0);
}

// ---------------- fp32 -> bf16 elementwise (x) ----------------
__global__ __launch_bounds__(256) void k_cvt_x(const float* __restrict__ x,
                                               unsigned short* __restrict__ xb, int n) {
    int idx = (blockIdx.x * 256 + threadIdx.x) * 4;
    if (idx < n) {
        float4 v = *(const float4*)(x + idx);
        us4 o;
        o.x = f2bf(v.x); o.y = f2bf(v.y); o.z = f2bf(v.z); o.w = f2bf(v.w);
        *(us4*)(xb + idx) = o;
    }
}

// ------------- fp32 [R][C] -> bf16 [C][R] (weights) -------------
__global__ __launch_bounds__(256) void k_transpose_w(const float* __restrict__ in,
                                                     unsigned short* __restrict__ out,
                                                     int R, int C) {
    __shared__ float tile[64][65];
    int c0 = blockIdx.x * 64, r0 = blockIdx.y * 64;
    int t = threadIdx.x;
    int tr = t >> 4, tc = (t & 15) * 4;
#pragma unroll
    for (int p = 0; p < 4; p++) {
        int row = p * 16 + tr;
        float4 v = *(const float4*)(in + (size_t)(r0 + row) * C + c0 + tc);
        tile[row][tc + 0] = v.x; tile[row][tc + 1] = v.y;
        tile[row][tc + 2] = v.z; tile[row][tc + 3] = v.w;
    }
    __syncthreads();
    int oc = t >> 4, orr = (t & 15) * 4;
#pragma unroll
    for (int p = 0; p < 4; p++) {
        int crow = p * 16 + oc;   // original column == output row
        us4 o;
        o.x = f2bf(tile[orr + 0][crow]);
        o.y = f2bf(tile[orr + 1][crow]);
        o.z = f2bf(tile[orr + 2][crow]);
        o.w = f2bf(tile[orr + 3][crow]);
        *(us4*)(out + (size_t)(c0 + crow) * R + r0 + orr) = o;
    }
}

// -------- 128x128 GEMM, BK=32, 3-buf ring, depth-2 counted-vmcnt pipeline --------
// MODE 0: A = xb [4096][1024], Bt = w1t [3072][1024]; epilogue: +b1,
//   q (scaled by 0.125*log2e) -> qh, k -> ks frag-interleaved, v -> vs frag-interleaved.
// MODE 1: A = attn [B*H][N][DH] (head-strided k), Bt = w2t [1024][1024];
//   epilogue: +b2 -> fp32 out [4096][1024].
// LDS linear; global SOURCE col-group pre-swizzled by ^(row&3); ds_read applies
// the same XOR -> 4-way instead of 16-way bank aliasing (m104-compliant).
template <int MODE>
__global__ __launch_bounds__(256) void k_gemm(const unsigned short* __restrict__ A,
                                              const unsigned short* __restrict__ Bt,
                                              const float* __restrict__ bias,
                                              unsigned short* __restrict__ qdst,
                                              unsigned short* __restrict__ kdst,
                                              unsigned short* __restrict__ vdst,
                                              float* __restrict__ outp) {
    __shared__ unsigned short As[3][128 * 32];
    __shared__ unsigned short Bs[3][128 * 32];
    const int K = 1024;
    const int NT = 32;                     // K / 32 k-tiles
    int tid = threadIdx.x;
    int lane = tid & 63, wv = tid >> 6;
    int wm = wv >> 1, wn = wv & 1;

    // flat grid + bijective XCD swizzle (nwg % 8 == 0)
    const int NX  = (MODE == 0) ? 24 : 8;        // n-tiles
    const int CPX = (MODE == 0) ? 96 : 32;       // nwg/8
    int F = blockIdx.x;
    int L = (F & 7) * CPX + (F >> 3);
    int n0 = (L % NX) * 128;
    int m0 = (L / NX) * 128;
    int bIdx = m0 >> 11;       // batch index (MODE 1)
    int ntok0 = m0 & 2047;

    f32x4 acc[4][4];
#pragma unroll
    for (int i = 0; i < 4; i++)
#pragma unroll
        for (int j = 0; j < 4; j++) {
            f32x4 z; z[0] = 0.f; z[1] = 0.f; z[2] = 0.f; z[3] = 0.f;
            acc[i][j] = z;
        }

    auto stage = [&](int buf, int tt) {    // k-tile tt -> buffer buf
        int k0 = tt * 32;
        const unsigned short* aptr;
        int arst;
        if (MODE == 0) { aptr = A + (size_t)m0 * K + k0; arst = K; }
        else {
            int hh = k0 >> 6;
            aptr = A + ((size_t)(bIdx * H_ + hh) * N_ + ntok0) * DH + (k0 & 63);
            arst = DH;
        }
        const unsigned short* bptr = Bt + (size_t)n0 * K + k0;
#pragma unroll
        for (int i = 0; i < 2; i++) {
            int cidb = i * 256 + wv * 64;          // wave-uniform chunk base
            int cid = cidb + lane;
            int row = cid >> 2;
            int cg  = (cid & 3) ^ (row & 3);       // pre-swizzled source col-group
            load_lds16(aptr + (size_t)row * arst + cg * 8, &As[buf][cidb * 8]);
            load_lds16(bptr + (size_t)row * K   + cg * 8, &Bs[buf][cidb * 8]);
        }
    };

    stage(0, 0);
    stage(1, 1);

    const int swz = ((lane >> 4) ^ (lane & 3)) * 8;   // swizzled k-offset (elems)
    const int ar0 = (wm * 64 + (lane & 15)) * 32 + swz;
    const int br0 = (wn * 64 + (lane & 15)) * 32 + swz;

#pragma unroll 1
    for (int t = 0; t < NT; ++t) {
        int cur = t % 3;
        if (t <= NT - 3) stage((t + 2) % 3, t + 2);
        // wait: stage(t) landed; stages t+1,t+2 (8 loads) stay in flight
        if (t <= NT - 3)      { VMCNT_ASM(8); }
        else if (t == NT - 2) { VMCNT_ASM(4); }
        else                  { VMCNT_ASM(0); }
        __builtin_amdgcn_s_barrier();          // all waves' slices of buf[cur] landed
        __builtin_amdgcn_sched_barrier(0);

        bf16x8 af[4], bfr[4];
#pragma unroll
        for (int mi = 0; mi < 4; mi++)
            af[mi] = *(const bf16x8*)&As[cur][ar0 + mi * 16 * 32];
#pragma unroll
        for (int ni = 0; ni < 4; ni++)
            bfr[ni] = *(const bf16x8*)&Bs[cur][br0 + ni * 16 * 32];
#pragma unroll
        for (int mi = 0; mi < 4; mi++)
#pragma unroll
            for (int ni = 0; ni < 4; ni++)
                acc[mi][ni] = __builtin_amdgcn_mfma_f32_16x16x32_bf16(
                    af[mi], bfr[ni], acc[mi][ni], 0, 0, 0);

        __builtin_amdgcn_s_barrier();          // reads of buf[cur] done -> reusable
    }

    // epilogue  (C/D: col = lane&15, row = (lane>>4)*4 + r)
#pragma unroll
    for (int ni = 0; ni < 4; ni++) {
        int col = n0 + wn * 64 + ni * 16 + (lane & 15);
        float bv = bias[col];
        if (MODE == 0) {
            int which = col >> 10;
            int hd = (col >> 6) & 15;
            int dh = col & 63;
            float scl = (which == 0) ? (0.125f * LOG2E) : 1.0f;
#pragma unroll
            for (int mi = 0; mi < 4; mi++) {
                int rbase = m0 + wm * 64 + mi * 16 + (lane >> 4) * 4;
#pragma unroll
                for (int r = 0; r < 4; r++) {
                    int tok = rbase + r;
                    int bb = tok >> 11, nn = tok & 2047;
                    float vvv = (acc[mi][ni][r] + bv) * scl;
                    size_t chunk = ((size_t)(bb * H_ + hd) * 64 + (nn >> 5)) * 2048;
                    if (which == 0) {
                        qdst[((size_t)(bb * H_ + hd) * N_ + nn) * DH + dh] = f2bf(vvv);
                    } else if (which == 1) {
                        // K fragment-INTERLEAVED: [frag][lane][8el]
                        int lane2 = ((dh >> 3) & 1) * 32 + (nn & 31);
                        kdst[chunk + (dh >> 4) * 512 + lane2 * 8 + (dh & 7)] = f2bf(vvv);
                    } else {
                        // V fragment-INTERLEAVED: [islot][lane][8el]
                        int lane2 = ((nn >> 3) & 1) * 32 + (dh & 31);
                        int islot = (dh >> 5) * 2 + ((nn >> 4) & 1);
                        vdst[chunk + islot * 512 + lane2 * 8 + (nn & 7)] = f2bf(vvv);
                    }
                }
            }
        } else {
#pragma unroll
            for (int mi = 0; mi < 4; mi++) {
                int rbase = m0 + wm * 64 + mi * 16 + (lane >> 4) * 4;
#pragma unroll
                for (int r = 0; r < 4; r++)
                    outp[(size_t)(rbase + r) * D_ + col] = acc[mi][ni][r] + bv;
            }
        }
    }
}

// ---------------- flash attention, LDS-staged K/V, 8 waves, KVBLK=64 ----------------
// qh: [B][H][N][DH] bf16 (scaled 0.125*log2e); ks, vs: fragment-interleaved
//   per-32kv chunk = 2048 el: frag*512 + lane*8 + elem (linear per 64-kv tile: 4096 el).
// o: [B*H][N][DH] bf16
__global__ __launch_bounds__(512, 2) void k_attn(const unsigned short* __restrict__ qh,
                                                 const unsigned short* __restrict__ ks,
                                                 const unsigned short* __restrict__ vs,
                                                 unsigned short* __restrict__ o) {
    __shared__ unsigned short kbuf[2][4096];
    __shared__ unsigned short vbuf[2][4096];
    int tid = threadIdx.x;
    int lane = tid & 63, wv = tid >> 6;      // wv 0..7
    // XCD swizzle: 256 blocks, XCD x gets logical L in [x*32,(x+1)*32) => bh in [4x,4x+4)
    int F = blockIdx.x;
    int L = (F & 7) * 32 + (F >> 3);
    int bh = L >> 3;
    int q0 = (L & 7) * 256 + wv * 32;
    int ln = lane & 31, hi = lane >> 5;
    const size_t bhO = (size_t)bh * N_ * DH;

    // Q fragments (B operand of mfma(K,Q)): lane owns q-row = ln
    const unsigned short* qp = qh + bhO;
    bf16x8 qf[4];
#pragma unroll
    for (int kk = 0; kk < 4; kk++)
        qf[kk] = *(const bf16x8*)(qp + (size_t)(q0 + ln) * DH + kk * 16 + hi * 8);

    const unsigned short* kg = ks + (size_t)bh * 131072;
    const unsigned short* vg = vs + (size_t)bh * 131072;

    f32x16 o0, o1;
#pragma unroll
    for (int r = 0; r < 16; r++) { o0[r] = 0.f; o1[r] = 0.f; }
    float m = -INFINITY, l = 0.f;

    // stage tile 0 (64 kv = 4096 el of K and of V; each wave stages its 1KB slice)
    load_lds16(kg + wv * 512 + lane * 8, &kbuf[0][wv * 512]);
    load_lds16(vg + wv * 512 + lane * 8, &vbuf[0][wv * 512]);
    __syncthreads();

#pragma unroll 1
    for (int t = 0; t < 32; ++t) {
        int b = t & 1;
        if (t < 31) {
            load_lds16(kg + (size_t)(t + 1) * 4096 + wv * 512 + lane * 8, &kbuf[b ^ 1][wv * 512]);
            load_lds16(vg + (size_t)(t + 1) * 4096 + wv * 512 + lane * 8, &vbuf[b ^ 1][wv * 512]);
        }

        // ---- QK^T: two independent 4-MFMA chains (kv chunks c0, c1) ----
        bf16x8 kfa[4], kfb[4];
#pragma unroll
        for (int i = 0; i < 4; i++) {
            kfa[i] = *(const bf16x8*)&kbuf[b][i * 512 + lane * 8];
            kfb[i] = *(const bf16x8*)&kbuf[b][2048 + i * 512 + lane * 8];
        }
        f32x16 sa, sb;
#pragma unroll
        for (int r = 0; r < 16; r++) { sa[r] = 0.f; sb[r] = 0.f; }
#pragma unroll
        for (int i = 0; i < 4; i++)
            sa = __builtin_amdgcn_mfma_f32_32x32x16_bf16(kfa[i], qf[i], sa, 0, 0, 0);
#pragma unroll
        for (int i = 0; i < 4; i++)
            sb = __builtin_amdgcn_mfma_f32_32x32x16_bf16(kfb[i], qf[i], sb, 0, 0, 0);
        // s[r] = S^T[kv][q] (log2 domain): q = ln, kv = (r&3)+8*(r>>2)+4*hi (+32 for sb)

        // ---- online softmax over 64 kv ----
        float mx[8];
#pragma unroll
        for (int i = 0; i < 8; i++)
            mx[i] = fmaxf(fmaxf(sa[i], sa[i + 8]), fmaxf(sb[i], sb[i + 8]));
#pragma unroll
        for (int i = 0; i < 4; i++) mx[i] = fmaxf(mx[i], mx[i + 4]);
        float mt = fmaxf(fmaxf(mx[0], mx[2]), fmaxf(mx[1], mx[3]));
        {   // cross-half (lane ^ 32) via permlane32_swap (VALU, no LDS)
            u32x2 sw = __builtin_amdgcn_permlane32_swap(f2u(mt), f2u(mt), false, false);
            mt = fmaxf(u2f(sw[0]), u2f(sw[1]));
        }
        if (!__all(mt <= m + 8.0f)) {   // defer-max, exp2 domain (p <= 2^8)
            float mn = fmaxf(m, mt);
            float fs = __builtin_amdgcn_exp2f(m - mn);
            m = mn;
            l *= fs;
#pragma unroll
            for (int r = 0; r < 16; r++) { o0[r] *= fs; o1[r] *= fs; }
        }
        float pa[16], pb[16];
#pragma unroll
        for (int r = 0; r < 16; r++) {
            pa[r] = __builtin_amdgcn_exp2f(sa[r] - m);
            pb[r] = __builtin_amdgcn_exp2f(sb[r] - m);
        }
        float sm[8];
#pragma unroll
        for (int i = 0; i < 8; i++) sm[i] = (pa[i] + pa[i + 8]) + (pb[i] + pb[i + 8]);
#pragma unroll
        for (int i = 0; i < 4; i++) sm[i] = sm[i] + sm[i + 4];
        float sum = (sm[0] + sm[2]) + (sm[1] + sm[3]);
        {
            u32x2 sw = __builtin_amdgcn_permlane32_swap(f2u(sum), f2u(sum), false, false);
            sum = u2f(sw[0]) + u2f(sw[1]);
        }
        l += sum;

        // ---- pack P -> bf16 PV B-operands (verified wiring) ----
        unsigned pka[8], pkb[8];
#pragma unroll
        for (int i = 0; i < 8; i++) {
            pka[i] = cvt_pk_bf16(pa[2 * i], pa[2 * i + 1]);
            pkb[i] = cvt_pk_bf16(pb[2 * i], pb[2 * i + 1]);
        }
        u32x2 s0 = __builtin_amdgcn_permlane32_swap(pka[0], pka[2], false, false);
        u32x2 s1 = __builtin_amdgcn_permlane32_swap(pka[1], pka[3], false, false);
        u32x2 s2 = __builtin_amdgcn_permlane32_swap(pka[4], pka[6], false, false);
        u32x2 s3 = __builtin_amdgcn_permlane32_swap(pka[5], pka[7], false, false);
        bf16x8 pf0 = frag_from_u32(s0[0], s1[0], s0[1], s1[1]);  // kv  0..15
        bf16x8 pf1 = frag_from_u32(s2[0], s3[0], s2[1], s3[1]);  // kv 16..31
        s0 = __builtin_amdgcn_permlane32_swap(pkb[0], pkb[2], false, false);
        s1 = __builtin_amdgcn_permlane32_swap(pkb[1], pkb[3], false, false);
        s2 = __builtin_amdgcn_permlane32_swap(pkb[4], pkb[6], false, false);
        s3 = __builtin_amdgcn_permlane32_swap(pkb[5], pkb[7], false, false);
        bf16x8 pf2 = frag_from_u32(s0[0], s1[0], s0[1], s1[1]);  // kv 32..47
        bf16x8 pf3 = frag_from_u32(s2[0], s3[0], s2[1], s3[1]);  // kv 48..63

        // ---- PV: O^T[d][q] += V^T[d][kv] * P^T[kv][q] ----
        bf16x8 vf0, vf1, vf2, vf3;
        vf0 = *(const bf16x8*)&vbuf[b][0 * 512 + lane * 8];          // c0, d 0..31, kv 0..15
        vf1 = *(const bf16x8*)&vbuf[b][1 * 512 + lane * 8];          // c0, d 0..31, kv16..31
        vf2 = *(const bf16x8*)&vbuf[b][2048 + 0 * 512 + lane * 8];   // c1, d 0..31, kv32..47
        vf3 = *(const bf16x8*)&vbuf[b][2048 + 1 * 512 + lane * 8];   // c1, d 0..31, kv48..63
        o0 = __builtin_amdgcn_mfma_f32_32x32x16_bf16(vf0, pf0, o0, 0, 0, 0);
        o0 = __builtin_amdgcn_mfma_f32_32x32x16_bf16(vf1, pf1, o0, 0, 0, 0);
        o0 = __builtin_amdgcn_mfma_f32_32x32x16_bf16(vf2, pf2, o0, 0, 0, 0);
        o0 = __builtin_amdgcn_mfma_f32_32x32x16_bf16(vf3, pf3, o0, 0, 0, 0);
        vf0 = *(const bf16x8*)&vbuf[b][2 * 512 + lane * 8];          // c0, d32..63, kv 0..15
        vf1 = *(const bf16x8*)&vbuf[b][3 * 512 + lane * 8];          // c0, d32..63, kv16..31
        vf2 = *(const bf16x8*)&vbuf[b][2048 + 2 * 512 + lane * 8];   // c1, d32..63, kv32..47
        vf3 = *(const bf16x8*)&vbuf[b][2048 + 3 * 512 + lane * 8];   // c1, d32..63, kv48..63
        o1 = __builtin_amdgcn_mfma_f32_32x32x16_bf16(vf0, pf0, o1, 0, 0, 0);
        o1 = __builtin_amdgcn_mfma_f32_32x32x16_bf16(vf1, pf1, o1, 0, 0, 0);
        o1 = __builtin_amdgcn_mfma_f32_32x32x16_bf16(vf2, pf2, o1, 0, 0, 0);
        o1 = __builtin_amdgcn_mfma_f32_32x32x16_bf16(vf3, pf3, o1, 0, 0, 0);

        __syncthreads();   // stage(t+1) landed (vmcnt drain) + all reads of buf[b] done
    }

    // epilogue: each wave owns its 32 q-rows fully
    float inv = 1.0f / l;
    unsigned short* ob = o + bhO + (size_t)(q0 + ln) * DH;
#pragma unroll
    for (int t2 = 0; t2 < 2; t2++) {
#pragma unroll
        for (int g = 0; g < 4; g++) {
            int d = t2 * 32 + g * 8 + hi * 4;   // rows: (r&3)+8*(r>>2)+4*hi
            int rb = g * 4;
            float a0 = (t2 ? o1[rb + 0] : o0[rb + 0]) * inv;
            float a1 = (t2 ? o1[rb + 1] : o0[rb + 1]) * inv;
            float a2 = (t2 ? o1[rb + 2] : o0[rb + 2]) * inv;
            float a3 = (t2 ? o1[rb + 3] : o0[rb + 3]) * inv;
            us4 w;
            w.x = f2bf(a0); w.y = f2bf(a1); w.z = f2bf(a2); w.w = f2bf(a3);
            *(us4*)(ob + d) = w;
        }
    }
}

extern "C" void kernel_launch(void* const* d_in, const int* in_sizes, int n_in,
                              void* d_out, int out_size, void* d_ws, size_t ws_size,
                              hipStream_t stream) {
    const float* x  = (const float*)d_in[0];
    const float* W1 = (const float*)d_in[1];
    const float* b1 = (const float*)d_in[2];
    const float* W2 = (const float*)d_in[3];
    const float* b2 = (const float*)d_in[4];
    float* out = (float*)d_out;

    char* ws = (char*)d_ws;
    unsigned short* xb   = (unsigned short*)(ws);                  //  8,388,608 B
    unsigned short* w1t  = (unsigned short*)(ws + 8388608);        //  6,291,456 B
    unsigned short* w2t  = (unsigned short*)(ws + 14680064);       //  2,097,152 B
    unsigned short* qh   = (unsigned short*)(ws + 16777216);       //  8,388,608 B
    unsigned short* ks   = (unsigned short*)(ws + 25165824);       //  8,388,608 B
    unsigned short* vsb  = (unsigned short*)(ws + 33554432);       //  8,388,608 B
    unsigned short* attn = (unsigned short*)(ws + 41943040);       //  8,388,608 B

    k_cvt_x<<<4096, 256, 0, stream>>>(x, xb, MTOK * D_);
    k_transpose_w<<<dim3(48, 16), 256, 0, stream>>>(W1, w1t, D_, 3 * D_);
    k_transpose_w<<<dim3(16, 16), 256, 0, stream>>>(W2, w2t, D_, D_);
    k_gemm<0><<<768, 256, 0, stream>>>(xb, w1t, b1, qh, ks, vsb, nullptr);
    k_attn<<<256, 512, 0, stream>>>(qh, ks, vsb, attn);
    k_gemm<1><<<256, 256, 0, stream>>>(attn, w2t, b2, nullptr, nullptr, nullptr, out);
}